// Round 2
// baseline (663.724 us; speedup 1.0000x reference)
//
#include <hip/hip_runtime.h>

// GCN forward on MI355X — bf16 intermediate pipeline.
//
// CSR build: per-workgroup bucket hist -> flat scan -> partition-private
// scatter -> per-bucket finalize (exclusive 64B-line ownership per writer).
//
// R6: CSR build was per-block-LATENCY-bound (R5 counters: fused kernel 126us
// with MfmaUtil 4% / VALUBusy 8% / HBM 19% / occ 25% -- all pipes idle, grid
// fully resident => straggler-block latency). Quarter the serial chain:
// BROWS 256->64 (1563 bucket blocks, 8 iter/pass), NPART 256->512 (scatter
// 25 iter). Bucket blocks dispatched FIRST in the fused kernel; gemm1
// backfills. Scan widened for TOT=800256 (scan2 @1024 threads).

#define NN 100000
#define NE 3200000
#define FIN 512
#define FHID 128
#define FOUT 32
#define BROWS 64           // rows per bucket
#define NBUCK 1563         // ceil(NN/64)
#define NPART 512          // scatter partitions (workgroups)
#define CHUNK 6250         // edges per partition; NPART*CHUNK == NE
#define TOT (NBUCK * NPART)  // 800256 counter cells
#define NSCAN1 782         // ceil(TOT/1024)
#define GG1 ((NN + 127) / 128)  // gemm1 blocks = 782

typedef __attribute__((ext_vector_type(8))) short bf16x8;
typedef __attribute__((ext_vector_type(4))) float f32x4;

static __device__ __forceinline__ unsigned short f2bf(float f) {
    unsigned u = __float_as_uint(f);
    unsigned r = (u + 0x7FFFu + ((u >> 16) & 1u)) >> 16;  // RTN-even
    return (unsigned short)r;
}
static __device__ __forceinline__ float bf2f(unsigned short u) {
    return __uint_as_float(((unsigned)u) << 16);
}
static __device__ __forceinline__ float bflo(unsigned u) {
    return __uint_as_float(u << 16);
}
static __device__ __forceinline__ float bfhi(unsigned u) {
    return __uint_as_float(u & 0xffff0000u);
}

// ---------------- CSR build phase 1: hist (+ fused W1 transpose) ----------------
__global__ __launch_bounds__(256) void fused_prep_hist(const float* __restrict__ W1,
                                                       unsigned short* __restrict__ W1t,
                                                       const int* __restrict__ erow,
                                                       int* __restrict__ cntG) {
    if (blockIdx.x < NPART) {
        __shared__ int c[NBUCK];
        const int t = threadIdx.x;
        const int w = blockIdx.x;
        for (int i = t; i < NBUCK; i += 256) c[i] = 0;
        __syncthreads();
        const int e0 = w * CHUNK;
        const int e1 = min(e0 + CHUNK, NE);
        for (int e = e0 + t; e < e1; e += 256) atomicAdd(&c[erow[e] >> 6], 1);
        __syncthreads();
        for (int i = t; i < NBUCK; i += 256) cntG[w * NBUCK + i] = c[i];
    } else {
        int t = (blockIdx.x - NPART) * 256 + threadIdx.x;
        int n = t & 127;
        int k = t >> 7;
        W1t[n * 512 + k] = f2bf(W1[k * 128 + n]);
    }
}

__global__ __launch_bounds__(256) void scan1_kernel(const int* __restrict__ cntG,
                                                    int* __restrict__ off,
                                                    int* __restrict__ partials) {
    __shared__ int s[256];
    int t = threadIdx.x;
    int i0 = blockIdx.x * 1024 + t * 4;
    int v[4];
#pragma unroll
    for (int j = 0; j < 4; ++j) {
        int i = i0 + j;
        // flat index i = b*NPART + w (bucket-major); cntG is [w][b]
        v[j] = (i < TOT) ? cntG[(i & (NPART - 1)) * NBUCK + (i >> 9)] : 0;
    }
    int lsum = v[0] + v[1] + v[2] + v[3];
    s[t] = lsum;
    __syncthreads();
    for (int o = 1; o < 256; o <<= 1) {
        int xv = (t >= o) ? s[t - o] : 0;
        __syncthreads();
        s[t] += xv;
        __syncthreads();
    }
    if (t == 255) partials[blockIdx.x] = s[255];
    int run = s[t] - lsum;
#pragma unroll
    for (int j = 0; j < 4; ++j) {
        if (i0 + j < TOT) off[i0 + j] = run;
        run += v[j];
    }
}

__global__ __launch_bounds__(1024) void scan2_kernel(int* partials) {
    __shared__ int s[1024];
    int t = threadIdx.x;
    int v = (t < NSCAN1) ? partials[t] : 0;
    s[t] = v;
    __syncthreads();
    for (int o = 1; o < 1024; o <<= 1) {
        int xv = (t >= o) ? s[t - o] : 0;
        __syncthreads();
        s[t] += xv;
        __syncthreads();
    }
    if (t < NSCAN1) partials[t] = s[t] - v;
}

__global__ __launch_bounds__(256) void scan3_kernel(int* __restrict__ off,
                                                    const int* __restrict__ partials) {
    int add = partials[blockIdx.x];
    int i0 = blockIdx.x * 1024 + threadIdx.x * 4;
#pragma unroll
    for (int j = 0; j < 4; ++j)
        if (i0 + j < TOT) off[i0 + j] += add;
}

__global__ __launch_bounds__(256) void scatter_part(const int* __restrict__ erow,
                                                    const int* __restrict__ ecol,
                                                    const float* __restrict__ eval,
                                                    const int* __restrict__ off,
                                                    int2* __restrict__ bcolval) {
    __shared__ int pos[NBUCK];
    const int t = threadIdx.x;
    const int w = blockIdx.x;
    for (int b = t; b < NBUCK; b += 256) pos[b] = off[b * NPART + w];
    __syncthreads();
    const int e0 = w * CHUNK;
    const int e1 = min(e0 + CHUNK, NE);
    for (int e = e0 + t; e < e1; e += 256) {
        int r = erow[e];
        int idx = atomicAdd(&pos[r >> 6], 1);
        bcolval[idx] = make_int2(ecol[e] | ((r & 63) << 20), __float_as_int(eval[e]));
    }
}

// ---------------- Fused: bucket_to_csr (first, straggler) || gemm1 (MFMA) ----------------
__global__ __launch_bounds__(256) void fused_csr_gemm1(
    const int* __restrict__ off, const int2* __restrict__ bcolval,
    int* __restrict__ rowptr, int2* __restrict__ epack,
    const float* __restrict__ x, const unsigned short* __restrict__ W1t,
    unsigned short* __restrict__ outd) {
    if (blockIdx.x >= NBUCK) {
        // ---- gemm1: support1(bf16) = x(f32) @ W1 ----
        __shared__ __align__(16) unsigned short As[128 * 32];
        const int tid = threadIdx.x;
        const int lane = tid & 63;
        const int w = __builtin_amdgcn_readfirstlane(tid >> 6);
        const int quad = lane >> 4;
        const int m = lane & 15;
        const int row0 = (blockIdx.x - NBUCK) * 128;

        f32x4 acc[8][2];
#pragma unroll
        for (int mt = 0; mt < 8; ++mt)
#pragma unroll
            for (int nt = 0; nt < 2; ++nt) acc[mt][nt] = (f32x4){0.f, 0.f, 0.f, 0.f};

        int srow[4], skq[4];
        const float* sptr[4];
#pragma unroll
        for (int s = 0; s < 4; ++s) {
            int f = tid + s * 256;
            srow[s] = f >> 3;
            skq[s] = f & 7;
            sptr[s] = x + (size_t)(row0 + srow[s]) * FIN + skq[s] * 4;
        }
        float4 ld[4];
#pragma unroll
        for (int s = 0; s < 4; ++s)
            ld[s] = (row0 + srow[s] < NN) ? *(const float4*)sptr[s]
                                          : make_float4(0.f, 0.f, 0.f, 0.f);

        for (int ks = 0; ks < 16; ++ks) {
            __syncthreads();
#pragma unroll
            for (int s = 0; s < 4; ++s) {
                int r = srow[s], kq = skq[s];
                int mt = r >> 4, mm = r & 15;
                int offs = mt * 512 + (kq >> 1) * 128 + mm * 8 + (kq & 1) * 4;
                ushort4 p;
                p.x = f2bf(ld[s].x);
                p.y = f2bf(ld[s].y);
                p.z = f2bf(ld[s].z);
                p.w = f2bf(ld[s].w);
                *(ushort4*)&As[offs] = p;
            }
            __syncthreads();
            if (ks < 15) {
#pragma unroll
                for (int s = 0; s < 4; ++s)
                    ld[s] = (row0 + srow[s] < NN)
                                ? *(const float4*)(sptr[s] + (ks + 1) * 32)
                                : make_float4(0.f, 0.f, 0.f, 0.f);
            }
            bf16x8 bfr[2];
#pragma unroll
            for (int nt = 0; nt < 2; ++nt) {
                int n = (w * 2 + nt) * 16 + m;
                bfr[nt] = *(const bf16x8*)(W1t + (size_t)n * 512 + ks * 32 + quad * 8);
            }
#pragma unroll
            for (int mt = 0; mt < 8; ++mt) {
                bf16x8 af = *(const bf16x8*)&As[mt * 512 + quad * 128 + m * 8];
                acc[mt][0] = __builtin_amdgcn_mfma_f32_16x16x32_bf16(af, bfr[0], acc[mt][0], 0, 0, 0);
                acc[mt][1] = __builtin_amdgcn_mfma_f32_16x16x32_bf16(af, bfr[1], acc[mt][1], 0, 0, 0);
            }
        }
#pragma unroll
        for (int mt = 0; mt < 8; ++mt)
#pragma unroll
            for (int nt = 0; nt < 2; ++nt) {
                int col = (w * 2 + nt) * 16 + m;
#pragma unroll
                for (int r = 0; r < 4; ++r) {
                    int row = row0 + mt * 16 + quad * 4 + r;
                    if (row < NN) outd[(size_t)row * FHID + col] = f2bf(acc[mt][nt][r]);
                }
            }
    } else {
        // ---- bucket_to_csr: 64-row buckets, 8 iter/pass ----
        __shared__ int cnt[BROWS];
        __shared__ int pos[BROWS];
        __shared__ int s[BROWS];
        const int b = blockIdx.x;
        const int t = threadIdx.x;
        const int s0 = off[b * NPART];
        const int send = (b == NBUCK - 1) ? NE : off[(b + 1) * NPART];
        const int n = send - s0;
        if (t < BROWS) cnt[t] = 0;
        __syncthreads();
        for (int i = t; i < n; i += 256)
            atomicAdd(&cnt[((unsigned)bcolval[s0 + i].x) >> 20], 1);
        __syncthreads();
        int myc = (t < BROWS) ? cnt[t] : 0;
        if (t < BROWS) s[t] = myc;
        __syncthreads();
        for (int o = 1; o < BROWS; o <<= 1) {
            int xv = (t >= o && t < BROWS) ? s[t - o] : 0;
            __syncthreads();
            if (t < BROWS) s[t] += xv;
            __syncthreads();
        }
        if (t < BROWS) {
            int excl = s[t] - myc;
            pos[t] = excl;
            int row = b * BROWS + t;
            if (row < NN) rowptr[row] = s0 + excl;
        }
        if (b == 0 && t == 0) rowptr[NN] = NE;
        __syncthreads();
        for (int i = t; i < n; i += 256) {
            int2 v = bcolval[s0 + i];
            int p = atomicAdd(&pos[((unsigned)v.x) >> 20], 1);
            epack[s0 + p] = make_int2(v.x & 0xFFFFF, v.y);
        }
    }
}

// ---------------- SpMM1 + bias + relu: h(bf16) = relu(A @ support1 + b1) ----------------
// Wave-per-row; edge descriptors wave-uniform via v_readlane (scalar path),
// 16 saddr-form 4B gathers in flight per wave.
__global__ __launch_bounds__(256) void spmm1_kernel(const int* __restrict__ rowptr,
                                                    const int2* __restrict__ epack,
                                                    const unsigned short* __restrict__ dense,
                                                    const float* __restrict__ b1,
                                                    unsigned short* __restrict__ h) {
    const int lane = threadIdx.x & 63;
    const int row = blockIdx.x * 4 + (threadIdx.x >> 6);
    const int start = __builtin_amdgcn_readfirstlane(rowptr[row]);
    const int cnt = __builtin_amdgcn_readfirstlane(rowptr[row + 1]) - start;
    const int sl16 = lane & 15;
    float acc0 = 0.f, acc1 = 0.f;

    for (int j = 0; j < cnt; j += 16) {
        int idx = j + sl16;
        idx = idx < cnt ? idx : cnt - 1;  // clamp: tail lanes re-read last desc
        const int2 p = epack[start + idx];
        const int rem = cnt - j;
        unsigned d[16];
#pragma unroll
        for (int k = 0; k < 16; ++k) {
            int col = __builtin_amdgcn_readlane(p.x, k);
            col = (k < rem) ? col : 0;  // tail: gather hot line 0, val=0 below
            d[k] = *((const unsigned*)(dense + ((size_t)col << 7)) + lane);
        }
#pragma unroll
        for (int k = 0; k < 16; ++k) {
            float v = (k < rem) ? __int_as_float(__builtin_amdgcn_readlane(p.y, k)) : 0.f;
            acc0 = fmaf(v, bflo(d[k]), acc0);
            acc1 = fmaf(v, bfhi(d[k]), acc1);
        }
    }
    float2 bb = *(const float2*)(b1 + lane * 2);
    unsigned r0 = f2bf(fmaxf(acc0 + bb.x, 0.f));
    unsigned r1 = f2bf(fmaxf(acc1 + bb.y, 0.f));
    *((unsigned*)(h + (size_t)row * FHID) + lane) = r0 | (r1 << 16);
}

// ---------------- GEMM2: support2(bf16) = h(bf16) @ W2(f32) ----------------
__global__ __launch_bounds__(256) void gemm2_kernel(const unsigned short* __restrict__ h,
                                                    const float* __restrict__ W2,
                                                    unsigned short* __restrict__ out) {
    __shared__ float hs[64][129];
    const int tid = threadIdx.x;
    const int lane = tid & 63;
    const int cg = __builtin_amdgcn_readfirstlane(tid >> 6);
    const int row0 = blockIdx.x * 64;
    const int row = row0 + lane;

    float acc[8];
#pragma unroll
    for (int c = 0; c < 8; ++c) acc[c] = 0.f;

#pragma unroll
    for (int j = 0; j < 8; ++j) {
        int f4 = tid + j * 256;
        int r = f4 >> 5;
        int kq = f4 & 31;
        ushort4 v = make_ushort4(0, 0, 0, 0);
        if (row0 + r < NN) v = *(const ushort4*)(h + (size_t)(row0 + r) * FHID + kq * 4);
        hs[r][kq * 4 + 0] = bf2f(v.x);
        hs[r][kq * 4 + 1] = bf2f(v.y);
        hs[r][kq * 4 + 2] = bf2f(v.z);
        hs[r][kq * 4 + 3] = bf2f(v.w);
    }
    __syncthreads();
#pragma unroll 4
    for (int k = 0; k < FHID; ++k) {
        float a = hs[lane][k];
        const float* wrow = W2 + k * FOUT + cg * 8;
#pragma unroll
        for (int c = 0; c < 8; ++c) acc[c] += a * wrow[c];
    }
    if (row < NN) {
        uint4 st;
        st.x = (unsigned)f2bf(acc[0]) | ((unsigned)f2bf(acc[1]) << 16);
        st.y = (unsigned)f2bf(acc[2]) | ((unsigned)f2bf(acc[3]) << 16);
        st.z = (unsigned)f2bf(acc[4]) | ((unsigned)f2bf(acc[5]) << 16);
        st.w = (unsigned)f2bf(acc[6]) | ((unsigned)f2bf(acc[7]) << 16);
        *(uint4*)(out + (size_t)row * FOUT + cg * 8) = st;
    }
}

// ------- SpMM2 + bias + log_softmax (fp32 out) -------
__global__ __launch_bounds__(256) void spmm2_kernel(const int* __restrict__ rowptr,
                                                    const int2* __restrict__ epack,
                                                    const unsigned short* __restrict__ dense,
                                                    const float* __restrict__ b2,
                                                    float* __restrict__ out) {
    const int lane = threadIdx.x & 63;
    const int row = blockIdx.x * 4 + (threadIdx.x >> 6);
    const int start = __builtin_amdgcn_readfirstlane(rowptr[row]);
    const int cnt = __builtin_amdgcn_readfirstlane(rowptr[row + 1]) - start;
    const int col = lane & 31;
    const int slot = lane >> 5;
    const int sl16 = lane & 15;
    float acc = 0.f;

    for (int j = 0; j < cnt; j += 16) {
        int idx = j + sl16;
        idx = idx < cnt ? idx : cnt - 1;
        const int2 p = epack[start + idx];
        const int rem = cnt - j;
        unsigned short d[8];
        float vv[8];
#pragma unroll
        for (int k = 0; k < 8; ++k) {
            int cA = __builtin_amdgcn_readlane(p.x, 2 * k);
            int cB = __builtin_amdgcn_readlane(p.x, 2 * k + 1);
            int ei = 2 * k + slot;
            int c = slot ? cB : cA;
            c = (ei < rem) ? c : 0;
            d[k] = *(dense + (size_t)c * FOUT + col);
            int vA = __builtin_amdgcn_readlane(p.y, 2 * k);
            int vB = __builtin_amdgcn_readlane(p.y, 2 * k + 1);
            float v = __int_as_float(slot ? vB : vA);
            vv[k] = (ei < rem) ? v : 0.f;
        }
#pragma unroll
        for (int k = 0; k < 8; ++k) acc = fmaf(vv[k], bf2f(d[k]), acc);
    }
    acc += __shfl_xor(acc, 32, 64);  // combine the two edge-slots per col
    acc += b2[col];
    float m = acc;
#pragma unroll
    for (int mask = 16; mask >= 1; mask >>= 1) m = fmaxf(m, __shfl_xor(m, mask, 64));
    float ex = expf(acc - m);
    float ssum = ex;
#pragma unroll
    for (int mask = 16; mask >= 1; mask >>= 1) ssum += __shfl_xor(ssum, mask, 64);
    float lse = m + logf(ssum);
    if (lane < 32) out[(size_t)row * FOUT + col] = acc - lse;
}

extern "C" void kernel_launch(void* const* d_in, const int* in_sizes, int n_in,
                              void* d_out, int out_size, void* d_ws, size_t ws_size,
                              hipStream_t stream) {
    const float* x = (const float*)d_in[0];
    const int* erow = (const int*)d_in[1];
    const int* ecol = (const int*)d_in[2];
    const float* eval = (const float*)d_in[3];
    const float* W1 = (const float*)d_in[4];
    const float* b1 = (const float*)d_in[5];
    const float* W2 = (const float*)d_in[6];
    const float* b2 = (const float*)d_in[7];
    float* out = (float*)d_out;

    char* ws = (char*)d_ws;
    size_t off_b = 0;
    auto walloc = [&](size_t bytes) -> void* {
        void* p = ws + off_b;
        off_b = (off_b + bytes + 255) & ~(size_t)255;
        return p;
    };
    int2* epack = (int2*)walloc((size_t)NE * 8);
    int* rowptr = (int*)walloc((size_t)(NN + 1) * 4);
    int* cntG = (int*)walloc((size_t)TOT * 4);
    int* off = (int*)walloc((size_t)TOT * 4);
    int* partials = (int*)walloc(4096);
    unsigned short* W1t = (unsigned short*)walloc((size_t)FHID * FIN * 2);
    // de-unioned: bucket_to_csr reads bcolval WHILE gemm1 writes support1
    int2* bcolval = (int2*)walloc((size_t)NE * 8);
    unsigned short* support1 = (unsigned short*)walloc((size_t)NN * FHID * 2);
    unsigned short* h = (unsigned short*)walloc((size_t)NN * FHID * 2);
    unsigned short* support2 = support1;  // support1 dead after spmm1

    fused_prep_hist<<<NPART + 256, 256, 0, stream>>>(W1, W1t, erow, cntG);
    scan1_kernel<<<NSCAN1, 256, 0, stream>>>(cntG, off, partials);
    scan2_kernel<<<1, 1024, 0, stream>>>(partials);
    scan3_kernel<<<NSCAN1, 256, 0, stream>>>(off, partials);
    scatter_part<<<NPART, 256, 0, stream>>>(erow, ecol, eval, off, bcolval);
    fused_csr_gemm1<<<NBUCK + GG1, 256, 0, stream>>>(off, bcolval, rowptr, epack,
                                                     x, W1t, support1);
    spmm1_kernel<<<NN / 4, 256, 0, stream>>>(rowptr, epack, support1, b1, h);
    gemm2_kernel<<<(NN + 63) / 64, 256, 0, stream>>>(h, W2, support2);
    spmm2_kernel<<<NN / 4, 256, 0, stream>>>(rowptr, epack, support2, b2, out);
}

// Round 3
// 657.053 us; speedup vs baseline: 1.0102x; 1.0102x over previous
//
#include <hip/hip_runtime.h>

// GCN forward on MI355X — bf16 intermediate pipeline.
//
// CSR build: per-workgroup bucket hist -> flat scan -> partition-private
// scatter -> per-bucket finalize (register-staged, LDS-reordered, coalesced
// epack writes).
//
// R7: R5/R6 proved fused_csr_gemm1's 126us is GEMM1 (bucket restructure 4x
// changed nothing). gemm1 was barrier/burst-drain latency-bound at 1.37TB/s
// (floor 34us for 205MB x). Rewrite: NO LDS, no barriers -- A-fragments
// loaded straight from x (waves own disjoint 32-row slices, depth-1 reg
// prefetch), W1t pre-shuffled into fragment-ordered 1KB chunks (coalesced
// 16B/lane B loads, L2-hot). bucket_to_csr split back out (attribution) and
// upgraded: edges cached in registers (1 global read), scatter via LDS,
// coalesced output copy.

#define NN 100000
#define NE 3200000
#define FIN 512
#define FHID 128
#define FOUT 32
#define BROWS 64           // rows per bucket
#define NBUCK 1563         // ceil(NN/64)
#define NPART 512          // scatter partitions (workgroups)
#define CHUNK 6250         // edges per partition; NPART*CHUNK == NE
#define TOT (NBUCK * NPART)  // 800256 counter cells
#define NSCAN1 782         // ceil(TOT/1024)
#define EBCAP 2560         // bucket LDS staging capacity (E[n]=2048, +11 sigma)

typedef __attribute__((ext_vector_type(8))) short bf16x8;
typedef __attribute__((ext_vector_type(4))) float f32x4;

static __device__ __forceinline__ unsigned short f2bf(float f) {
    unsigned u = __float_as_uint(f);
    unsigned r = (u + 0x7FFFu + ((u >> 16) & 1u)) >> 16;  // RTN-even
    return (unsigned short)r;
}
static __device__ __forceinline__ float bf2f(unsigned short u) {
    return __uint_as_float(((unsigned)u) << 16);
}
static __device__ __forceinline__ float bflo(unsigned u) {
    return __uint_as_float(u << 16);
}
static __device__ __forceinline__ float bfhi(unsigned u) {
    return __uint_as_float(u & 0xffff0000u);
}
static __device__ __forceinline__ bf16x8 pack8(float4 u, float4 v) {
    bf16x8 r;
    r[0] = (short)f2bf(u.x); r[1] = (short)f2bf(u.y);
    r[2] = (short)f2bf(u.z); r[3] = (short)f2bf(u.w);
    r[4] = (short)f2bf(v.x); r[5] = (short)f2bf(v.y);
    r[6] = (short)f2bf(v.z); r[7] = (short)f2bf(v.w);
    return r;
}

// ---------------- CSR build phase 1: hist (+ fused W1 fragment-shuffle) ----------------
// W1t layout: 16B chunk c = (nt*16 + ks)*64 + lane; chunk holds bf16 of
// W1[ks*32 + (lane>>4)*8 + j][nt*16 + (lane&15)], j=0..7 -- exactly the
// MFMA B-fragment wave order, so gemm1's B load is 16B/lane coalesced.
__global__ __launch_bounds__(256) void fused_prep_hist(const float* __restrict__ W1,
                                                       unsigned short* __restrict__ W1t,
                                                       const int* __restrict__ erow,
                                                       int* __restrict__ cntG) {
    if (blockIdx.x < NPART) {
        __shared__ int c[NBUCK];
        const int t = threadIdx.x;
        const int w = blockIdx.x;
        for (int i = t; i < NBUCK; i += 256) c[i] = 0;
        __syncthreads();
        const int e0 = w * CHUNK;
        const int e1 = min(e0 + CHUNK, NE);
        for (int e = e0 + t; e < e1; e += 256) atomicAdd(&c[erow[e] >> 6], 1);
        __syncthreads();
        for (int i = t; i < NBUCK; i += 256) cntG[w * NBUCK + i] = c[i];
    } else {
        int t = (blockIdx.x - NPART) * 256 + threadIdx.x;  // 65536 threads
        int j = t & 7;
        int c = t >> 3;
        int l = c & 63;
        int ks = (c >> 6) & 15;
        int nt = c >> 10;
        int n = nt * 16 + (l & 15);
        int k = ks * 32 + ((l >> 4) << 3) + j;
        W1t[(size_t)c * 8 + j] = f2bf(W1[k * FHID + n]);
    }
}

__global__ __launch_bounds__(256) void scan1_kernel(const int* __restrict__ cntG,
                                                    int* __restrict__ off,
                                                    int* __restrict__ partials) {
    __shared__ int s[256];
    int t = threadIdx.x;
    int i0 = blockIdx.x * 1024 + t * 4;
    int v[4];
#pragma unroll
    for (int j = 0; j < 4; ++j) {
        int i = i0 + j;
        // flat index i = b*NPART + w (bucket-major); cntG is [w][b]
        v[j] = (i < TOT) ? cntG[(i & (NPART - 1)) * NBUCK + (i >> 9)] : 0;
    }
    int lsum = v[0] + v[1] + v[2] + v[3];
    s[t] = lsum;
    __syncthreads();
    for (int o = 1; o < 256; o <<= 1) {
        int xv = (t >= o) ? s[t - o] : 0;
        __syncthreads();
        s[t] += xv;
        __syncthreads();
    }
    if (t == 255) partials[blockIdx.x] = s[255];
    int run = s[t] - lsum;
#pragma unroll
    for (int j = 0; j < 4; ++j) {
        if (i0 + j < TOT) off[i0 + j] = run;
        run += v[j];
    }
}

__global__ __launch_bounds__(1024) void scan2_kernel(int* partials) {
    __shared__ int s[1024];
    int t = threadIdx.x;
    int v = (t < NSCAN1) ? partials[t] : 0;
    s[t] = v;
    __syncthreads();
    for (int o = 1; o < 1024; o <<= 1) {
        int xv = (t >= o) ? s[t - o] : 0;
        __syncthreads();
        s[t] += xv;
        __syncthreads();
    }
    if (t < NSCAN1) partials[t] = s[t] - v;
}

__global__ __launch_bounds__(256) void scan3_kernel(int* __restrict__ off,
                                                    const int* __restrict__ partials) {
    int add = partials[blockIdx.x];
    int i0 = blockIdx.x * 1024 + threadIdx.x * 4;
#pragma unroll
    for (int j = 0; j < 4; ++j)
        if (i0 + j < TOT) off[i0 + j] += add;
}

__global__ __launch_bounds__(256) void scatter_part(const int* __restrict__ erow,
                                                    const int* __restrict__ ecol,
                                                    const float* __restrict__ eval,
                                                    const int* __restrict__ off,
                                                    int2* __restrict__ bcolval) {
    __shared__ int pos[NBUCK];
    const int t = threadIdx.x;
    const int w = blockIdx.x;
    for (int b = t; b < NBUCK; b += 256) pos[b] = off[b * NPART + w];
    __syncthreads();
    const int e0 = w * CHUNK;
    const int e1 = min(e0 + CHUNK, NE);
    for (int e = e0 + t; e < e1; e += 256) {
        int r = erow[e];
        int idx = atomicAdd(&pos[r >> 6], 1);
        bcolval[idx] = make_int2(ecol[e] | ((r & 63) << 20), __float_as_int(eval[e]));
    }
}

// ---------------- bucket_to_csr: 64-row buckets ----------------
// bcolval read ONCE into registers; row-sort scatter goes through LDS;
// epack written coalesced. Fallback to direct global scatter if a bucket
// overflows EBCAP (data-dependent; E[n]=2048, cap = +11 sigma).
__global__ __launch_bounds__(256) void bucket_to_csr(const int* __restrict__ off,
                                                     const int2* __restrict__ bcolval,
                                                     int* __restrict__ rowptr,
                                                     int2* __restrict__ epack) {
    __shared__ int cnt[BROWS];
    __shared__ int pos[BROWS];
    __shared__ int s[BROWS];
    __shared__ int2 eb[EBCAP];
    const int b = blockIdx.x;
    const int t = threadIdx.x;
    const int s0 = off[b * NPART];
    const int send = (b == NBUCK - 1) ? NE : off[(b + 1) * NPART];
    const int n = send - s0;
    const bool fits = (n <= EBCAP);
    if (t < BROWS) cnt[t] = 0;
    __syncthreads();
    int2 myv[10];
    if (fits) {
#pragma unroll
        for (int ii = 0; ii < 10; ++ii) {
            int i = t + ii * 256;
            int2 v = make_int2(0, 0);
            if (i < n) {
                v = bcolval[s0 + i];
                atomicAdd(&cnt[((unsigned)v.x) >> 20], 1);
            }
            myv[ii] = v;
        }
    } else {
        for (int i = t; i < n; i += 256)
            atomicAdd(&cnt[((unsigned)bcolval[s0 + i].x) >> 20], 1);
    }
    __syncthreads();
    int myc = (t < BROWS) ? cnt[t] : 0;
    if (t < BROWS) s[t] = myc;
    __syncthreads();
    for (int o = 1; o < BROWS; o <<= 1) {
        int xv = (t >= o && t < BROWS) ? s[t - o] : 0;
        __syncthreads();
        if (t < BROWS) s[t] += xv;
        __syncthreads();
    }
    if (t < BROWS) {
        int excl = s[t] - myc;
        pos[t] = excl;  // bucket-relative
        int row = b * BROWS + t;
        if (row < NN) rowptr[row] = s0 + excl;
    }
    if (b == 0 && t == 0) rowptr[NN] = NE;
    __syncthreads();
    if (fits) {
#pragma unroll
        for (int ii = 0; ii < 10; ++ii) {
            int i = t + ii * 256;
            if (i < n) {
                int2 v = myv[ii];
                int p = atomicAdd(&pos[((unsigned)v.x) >> 20], 1);
                eb[p] = make_int2(v.x & 0xFFFFF, v.y);
            }
        }
        __syncthreads();
        for (int i = t; i < n; i += 256) epack[s0 + i] = eb[i];
    } else {
        for (int i = t; i < n; i += 256) {
            int2 v = bcolval[s0 + i];
            int p = atomicAdd(&pos[((unsigned)v.x) >> 20], 1);
            epack[s0 + p] = make_int2(v.x & 0xFFFFF, v.y);
        }
    }
}

// ---------------- GEMM1 (MFMA, no LDS): support1(bf16) = x(f32) @ W1 ----------------
// 4 waves/block, wave owns 32 rows (2 m-tiles) x 128 cols (8 n-tiles).
// A-fragment loaded straight from x: lane(m,quad) reads x[row..][ks*32 +
// quad*8 ..+8] (2x float4), depth-1 register prefetch, no barriers -- loads
// stay in flight continuously. B from pre-shuffled W1t: 16B/lane coalesced,
// L2-resident (128KB table).
__global__ __launch_bounds__(256) void gemm1_mfma(const float* __restrict__ x,
                                                  const unsigned short* __restrict__ W1t,
                                                  unsigned short* __restrict__ out) {
    const int tid = threadIdx.x;
    const int lane = tid & 63;
    const int w = tid >> 6;
    const int quad = lane >> 4;
    const int m = lane & 15;
    const int row0 = blockIdx.x * 128 + w * 32;

    int rA = row0 + m;
    int rB = row0 + 16 + m;
    rA = rA < NN ? rA : NN - 1;  // clamp loads; stores guarded
    rB = rB < NN ? rB : NN - 1;
    const float* pA = x + (size_t)rA * FIN + quad * 8;
    const float* pB = x + (size_t)rB * FIN + quad * 8;

    f32x4 acc[2][8];
#pragma unroll
    for (int i = 0; i < 2; ++i)
#pragma unroll
        for (int nt = 0; nt < 8; ++nt) acc[i][nt] = (f32x4){0.f, 0.f, 0.f, 0.f};

    float4 a0 = *(const float4*)pA;
    float4 a1 = *(const float4*)(pA + 4);
    float4 b0 = *(const float4*)pB;
    float4 b1 = *(const float4*)(pB + 4);

    for (int ks = 0; ks < 16; ++ks) {
        const int kn = (ks + 1) & 15;  // last-iter prefetch wraps (discarded)
        float4 na0 = *(const float4*)(pA + kn * 32);
        float4 na1 = *(const float4*)(pA + kn * 32 + 4);
        float4 nb0 = *(const float4*)(pB + kn * 32);
        float4 nb1 = *(const float4*)(pB + kn * 32 + 4);

        bf16x8 fA = pack8(a0, a1);
        bf16x8 fB = pack8(b0, b1);
        bf16x8 bb[8];
#pragma unroll
        for (int nt = 0; nt < 8; ++nt)
            bb[nt] = *(const bf16x8*)(W1t + ((size_t)((nt * 16 + ks) * 64 + lane)) * 8);
#pragma unroll
        for (int nt = 0; nt < 8; ++nt) {
            acc[0][nt] = __builtin_amdgcn_mfma_f32_16x16x32_bf16(fA, bb[nt], acc[0][nt], 0, 0, 0);
            acc[1][nt] = __builtin_amdgcn_mfma_f32_16x16x32_bf16(fB, bb[nt], acc[1][nt], 0, 0, 0);
        }
        a0 = na0; a1 = na1; b0 = nb0; b1 = nb1;
    }

    const int crow0 = blockIdx.x * 128 + w * 32;
#pragma unroll
    for (int i = 0; i < 2; ++i)
#pragma unroll
        for (int nt = 0; nt < 8; ++nt) {
            int col = nt * 16 + m;
#pragma unroll
            for (int r = 0; r < 4; ++r) {
                int row = crow0 + i * 16 + quad * 4 + r;
                if (row < NN) out[(size_t)row * FHID + col] = f2bf(acc[i][nt][r]);
            }
        }
}

// ---------------- SpMM1 + bias + relu: h(bf16) = relu(A @ support1 + b1) ----------------
// Wave-per-row; edge descriptors wave-uniform via v_readlane (scalar path),
// 16 saddr-form 4B gathers in flight per wave.
__global__ __launch_bounds__(256) void spmm1_kernel(const int* __restrict__ rowptr,
                                                    const int2* __restrict__ epack,
                                                    const unsigned short* __restrict__ dense,
                                                    const float* __restrict__ b1,
                                                    unsigned short* __restrict__ h) {
    const int lane = threadIdx.x & 63;
    const int row = blockIdx.x * 4 + (threadIdx.x >> 6);
    const int start = __builtin_amdgcn_readfirstlane(rowptr[row]);
    const int cnt = __builtin_amdgcn_readfirstlane(rowptr[row + 1]) - start;
    const int sl16 = lane & 15;
    float acc0 = 0.f, acc1 = 0.f;

    for (int j = 0; j < cnt; j += 16) {
        int idx = j + sl16;
        idx = idx < cnt ? idx : cnt - 1;  // clamp: tail lanes re-read last desc
        const int2 p = epack[start + idx];
        const int rem = cnt - j;
        unsigned d[16];
#pragma unroll
        for (int k = 0; k < 16; ++k) {
            int col = __builtin_amdgcn_readlane(p.x, k);
            col = (k < rem) ? col : 0;  // tail: gather hot line 0, val=0 below
            d[k] = *((const unsigned*)(dense + ((size_t)col << 7)) + lane);
        }
#pragma unroll
        for (int k = 0; k < 16; ++k) {
            float v = (k < rem) ? __int_as_float(__builtin_amdgcn_readlane(p.y, k)) : 0.f;
            acc0 = fmaf(v, bflo(d[k]), acc0);
            acc1 = fmaf(v, bfhi(d[k]), acc1);
        }
    }
    float2 bb = *(const float2*)(b1 + lane * 2);
    unsigned r0 = f2bf(fmaxf(acc0 + bb.x, 0.f));
    unsigned r1 = f2bf(fmaxf(acc1 + bb.y, 0.f));
    *((unsigned*)(h + (size_t)row * FHID) + lane) = r0 | (r1 << 16);
}

// ---------------- GEMM2: support2(bf16) = h(bf16) @ W2(f32) ----------------
__global__ __launch_bounds__(256) void gemm2_kernel(const unsigned short* __restrict__ h,
                                                    const float* __restrict__ W2,
                                                    unsigned short* __restrict__ out) {
    __shared__ float hs[64][129];
    const int tid = threadIdx.x;
    const int lane = tid & 63;
    const int cg = __builtin_amdgcn_readfirstlane(tid >> 6);
    const int row0 = blockIdx.x * 64;
    const int row = row0 + lane;

    float acc[8];
#pragma unroll
    for (int c = 0; c < 8; ++c) acc[c] = 0.f;

#pragma unroll
    for (int j = 0; j < 8; ++j) {
        int f4 = tid + j * 256;
        int r = f4 >> 5;
        int kq = f4 & 31;
        ushort4 v = make_ushort4(0, 0, 0, 0);
        if (row0 + r < NN) v = *(const ushort4*)(h + (size_t)(row0 + r) * FHID + kq * 4);
        hs[r][kq * 4 + 0] = bf2f(v.x);
        hs[r][kq * 4 + 1] = bf2f(v.y);
        hs[r][kq * 4 + 2] = bf2f(v.z);
        hs[r][kq * 4 + 3] = bf2f(v.w);
    }
    __syncthreads();
#pragma unroll 4
    for (int k = 0; k < FHID; ++k) {
        float a = hs[lane][k];
        const float* wrow = W2 + k * FOUT + cg * 8;
#pragma unroll
        for (int c = 0; c < 8; ++c) acc[c] += a * wrow[c];
    }
    if (row < NN) {
        uint4 st;
        st.x = (unsigned)f2bf(acc[0]) | ((unsigned)f2bf(acc[1]) << 16);
        st.y = (unsigned)f2bf(acc[2]) | ((unsigned)f2bf(acc[3]) << 16);
        st.z = (unsigned)f2bf(acc[4]) | ((unsigned)f2bf(acc[5]) << 16);
        st.w = (unsigned)f2bf(acc[6]) | ((unsigned)f2bf(acc[7]) << 16);
        *(uint4*)(out + (size_t)row * FOUT + cg * 8) = st;
    }
}

// ------- SpMM2 + bias + log_softmax (fp32 out) -------
__global__ __launch_bounds__(256) void spmm2_kernel(const int* __restrict__ rowptr,
                                                    const int2* __restrict__ epack,
                                                    const unsigned short* __restrict__ dense,
                                                    const float* __restrict__ b2,
                                                    float* __restrict__ out) {
    const int lane = threadIdx.x & 63;
    const int row = blockIdx.x * 4 + (threadIdx.x >> 6);
    const int start = __builtin_amdgcn_readfirstlane(rowptr[row]);
    const int cnt = __builtin_amdgcn_readfirstlane(rowptr[row + 1]) - start;
    const int col = lane & 31;
    const int slot = lane >> 5;
    const int sl16 = lane & 15;
    float acc = 0.f;

    for (int j = 0; j < cnt; j += 16) {
        int idx = j + sl16;
        idx = idx < cnt ? idx : cnt - 1;
        const int2 p = epack[start + idx];
        const int rem = cnt - j;
        unsigned short d[8];
        float vv[8];
#pragma unroll
        for (int k = 0; k < 8; ++k) {
            int cA = __builtin_amdgcn_readlane(p.x, 2 * k);
            int cB = __builtin_amdgcn_readlane(p.x, 2 * k + 1);
            int ei = 2 * k + slot;
            int c = slot ? cB : cA;
            c = (ei < rem) ? c : 0;
            d[k] = *(dense + (size_t)c * FOUT + col);
            int vA = __builtin_amdgcn_readlane(p.y, 2 * k);
            int vB = __builtin_amdgcn_readlane(p.y, 2 * k + 1);
            float v = __int_as_float(slot ? vB : vA);
            vv[k] = (ei < rem) ? v : 0.f;
        }
#pragma unroll
        for (int k = 0; k < 8; ++k) acc = fmaf(vv[k], bf2f(d[k]), acc);
    }
    acc += __shfl_xor(acc, 32, 64);  // combine the two edge-slots per col
    acc += b2[col];
    float m = acc;
#pragma unroll
    for (int mask = 16; mask >= 1; mask >>= 1) m = fmaxf(m, __shfl_xor(m, mask, 64));
    float ex = expf(acc - m);
    float ssum = ex;
#pragma unroll
    for (int mask = 16; mask >= 1; mask >>= 1) ssum += __shfl_xor(ssum, mask, 64);
    float lse = m + logf(ssum);
    if (lane < 32) out[(size_t)row * FOUT + col] = acc - lse;
}

extern "C" void kernel_launch(void* const* d_in, const int* in_sizes, int n_in,
                              void* d_out, int out_size, void* d_ws, size_t ws_size,
                              hipStream_t stream) {
    const float* x = (const float*)d_in[0];
    const int* erow = (const int*)d_in[1];
    const int* ecol = (const int*)d_in[2];
    const float* eval = (const float*)d_in[3];
    const float* W1 = (const float*)d_in[4];
    const float* b1 = (const float*)d_in[5];
    const float* W2 = (const float*)d_in[6];
    const float* b2 = (const float*)d_in[7];
    float* out = (float*)d_out;

    char* ws = (char*)d_ws;
    size_t off_b = 0;
    auto walloc = [&](size_t bytes) -> void* {
        void* p = ws + off_b;
        off_b = (off_b + bytes + 255) & ~(size_t)255;
        return p;
    };
    int2* epack = (int2*)walloc((size_t)NE * 8);
    int* rowptr = (int*)walloc((size_t)(NN + 1) * 4);
    int* cntG = (int*)walloc((size_t)TOT * 4);
    int* off = (int*)walloc((size_t)TOT * 4);
    int* partials = (int*)walloc(4096);
    unsigned short* W1t = (unsigned short*)walloc((size_t)FHID * FIN * 2);
    int2* bcolval = (int2*)walloc((size_t)NE * 8);
    unsigned short* support1 = (unsigned short*)walloc((size_t)NN * FHID * 2);
    unsigned short* h = (unsigned short*)walloc((size_t)NN * FHID * 2);
    unsigned short* support2 = support1;  // support1 dead after spmm1

    fused_prep_hist<<<NPART + 256, 256, 0, stream>>>(W1, W1t, erow, cntG);
    scan1_kernel<<<NSCAN1, 256, 0, stream>>>(cntG, off, partials);
    scan2_kernel<<<1, 1024, 0, stream>>>(partials);
    scan3_kernel<<<NSCAN1, 256, 0, stream>>>(off, partials);
    scatter_part<<<NPART, 256, 0, stream>>>(erow, ecol, eval, off, bcolval);
    bucket_to_csr<<<NBUCK, 256, 0, stream>>>(off, bcolval, rowptr, epack);
    gemm1_mfma<<<(NN + 127) / 128, 256, 0, stream>>>(x, W1t, support1);
    spmm1_kernel<<<NN / 4, 256, 0, stream>>>(rowptr, epack, support1, b1, h);
    gemm2_kernel<<<(NN + 63) / 64, 256, 0, stream>>>(h, W2, support2);
    spmm2_kernel<<<NN / 4, 256, 0, stream>>>(rowptr, epack, support2, b2, out);
}

// Round 4
// 644.631 us; speedup vs baseline: 1.0296x; 1.0193x over previous
//
#include <hip/hip_runtime.h>

// GCN forward on MI355X — bf16 intermediate pipeline.
//
// R8: attribution-blind => parallel latency attacks.
// (1) scatter_part fused || gemm1 (R5 proved heterogeneous-grid fusion hides
//     the latency-bound partner under the streaming one).
// (2) NPART 512->256: restore 64B write-run exclusivity (R0 measured 8x
//     write amplification for sub-line scattered writes; R6's NPART=512 made
//     runs 32B).
// (3) spmm1: 32-edge unrolled chunks (8KB gathers in flight/wave), full/tail
//     split removes per-iter cndmask selects. spmm2: dword gathers, 1
//     row/wave (25000 blocks), quad-parallel edges.
// (4) 9 launches.

#define NN 100000
#define NE 3200000
#define FIN 512
#define FHID 128
#define FOUT 32
#define BROWS 64             // rows per bucket
#define NBUCK 1563           // ceil(NN/64)
#define NPART 256            // scatter partitions (64B run exclusivity)
#define CHUNK 12800          // edges per partition; NPART*CHUNK == NE
#define TOT (NBUCK * NPART)  // 400128 counter cells
#define NSCAN1 391           // ceil(TOT/1024)
#define GG1 ((NN + 127) / 128)  // gemm1 blocks = 782
#define EBCAP 2560           // bucket LDS staging capacity (E[n]=2048)

typedef __attribute__((ext_vector_type(8))) short bf16x8;
typedef __attribute__((ext_vector_type(4))) float f32x4;

static __device__ __forceinline__ unsigned short f2bf(float f) {
    unsigned u = __float_as_uint(f);
    unsigned r = (u + 0x7FFFu + ((u >> 16) & 1u)) >> 16;  // RTN-even
    return (unsigned short)r;
}
static __device__ __forceinline__ float bf2f(unsigned short u) {
    return __uint_as_float(((unsigned)u) << 16);
}
static __device__ __forceinline__ float bflo(unsigned u) {
    return __uint_as_float(u << 16);
}
static __device__ __forceinline__ float bfhi(unsigned u) {
    return __uint_as_float(u & 0xffff0000u);
}
static __device__ __forceinline__ bf16x8 pack8(float4 u, float4 v) {
    bf16x8 r;
    r[0] = (short)f2bf(u.x); r[1] = (short)f2bf(u.y);
    r[2] = (short)f2bf(u.z); r[3] = (short)f2bf(u.w);
    r[4] = (short)f2bf(v.x); r[5] = (short)f2bf(v.y);
    r[6] = (short)f2bf(v.z); r[7] = (short)f2bf(v.w);
    return r;
}

// ---------------- CSR build phase 1: hist (+ fused W1 fragment-shuffle) ----------------
// W1t layout: 16B chunk c = (nt*16 + ks)*64 + lane; chunk holds bf16 of
// W1[ks*32 + (lane>>4)*8 + j][nt*16 + (lane&15)], j=0..7 -- the MFMA
// B-fragment wave order, so gemm1's B load is 16B/lane coalesced.
__global__ __launch_bounds__(256) void fused_prep_hist(const float* __restrict__ W1,
                                                       unsigned short* __restrict__ W1t,
                                                       const int* __restrict__ erow,
                                                       int* __restrict__ cntG) {
    if (blockIdx.x < NPART) {
        __shared__ int c[NBUCK];
        const int t = threadIdx.x;
        const int w = blockIdx.x;
        for (int i = t; i < NBUCK; i += 256) c[i] = 0;
        __syncthreads();
        const int e0 = w * CHUNK;
        const int e1 = min(e0 + CHUNK, NE);
        for (int e = e0 + t; e < e1; e += 256) atomicAdd(&c[erow[e] >> 6], 1);
        __syncthreads();
        for (int i = t; i < NBUCK; i += 256) cntG[w * NBUCK + i] = c[i];
    } else {
        int t = (blockIdx.x - NPART) * 256 + threadIdx.x;  // 65536 threads
        int j = t & 7;
        int c = t >> 3;
        int l = c & 63;
        int ks = (c >> 6) & 15;
        int nt = c >> 10;
        int n = nt * 16 + (l & 15);
        int k = ks * 32 + ((l >> 4) << 3) + j;
        W1t[(size_t)c * 8 + j] = f2bf(W1[k * FHID + n]);
    }
}

__global__ __launch_bounds__(256) void scan1_kernel(const int* __restrict__ cntG,
                                                    int* __restrict__ off,
                                                    int* __restrict__ partials) {
    __shared__ int s[256];
    int t = threadIdx.x;
    int i0 = blockIdx.x * 1024 + t * 4;
    int v[4];
#pragma unroll
    for (int j = 0; j < 4; ++j) {
        int i = i0 + j;
        // flat index i = b*NPART + w (bucket-major); cntG is [w][b]
        v[j] = (i < TOT) ? cntG[(i & (NPART - 1)) * NBUCK + (i >> 8)] : 0;
    }
    int lsum = v[0] + v[1] + v[2] + v[3];
    s[t] = lsum;
    __syncthreads();
    for (int o = 1; o < 256; o <<= 1) {
        int xv = (t >= o) ? s[t - o] : 0;
        __syncthreads();
        s[t] += xv;
        __syncthreads();
    }
    if (t == 255) partials[blockIdx.x] = s[255];
    int run = s[t] - lsum;
#pragma unroll
    for (int j = 0; j < 4; ++j) {
        if (i0 + j < TOT) off[i0 + j] = run;
        run += v[j];
    }
}

__global__ __launch_bounds__(512) void scan2_kernel(int* partials) {
    __shared__ int s[512];
    int t = threadIdx.x;
    int v = (t < NSCAN1) ? partials[t] : 0;
    s[t] = v;
    __syncthreads();
    for (int o = 1; o < 512; o <<= 1) {
        int xv = (t >= o) ? s[t - o] : 0;
        __syncthreads();
        s[t] += xv;
        __syncthreads();
    }
    if (t < NSCAN1) partials[t] = s[t] - v;
}

__global__ __launch_bounds__(256) void scan3_kernel(int* __restrict__ off,
                                                    const int* __restrict__ partials) {
    int add = partials[blockIdx.x];
    int i0 = blockIdx.x * 1024 + threadIdx.x * 4;
#pragma unroll
    for (int j = 0; j < 4; ++j)
        if (i0 + j < TOT) off[i0 + j] += add;
}

// ---------------- Fused: scatter_part (straggler, first) || gemm1 (MFMA) ----------------
__global__ __launch_bounds__(256) void fused_scatter_gemm1(
    const int* __restrict__ erow, const int* __restrict__ ecol,
    const float* __restrict__ eval, const int* __restrict__ off,
    int2* __restrict__ bcolval,
    const float* __restrict__ x, const unsigned short* __restrict__ W1t,
    unsigned short* __restrict__ outd) {
    if (blockIdx.x < NPART) {
        // ---- scatter: partition-private cursors, 64B run exclusivity ----
        __shared__ int pos[NBUCK];
        const int t = threadIdx.x;
        const int w = blockIdx.x;
        for (int b = t; b < NBUCK; b += 256) pos[b] = off[b * NPART + w];
        __syncthreads();
        const int e0 = w * CHUNK;
        const int e1 = min(e0 + CHUNK, NE);
        for (int e = e0 + t; e < e1; e += 256) {
            int r = erow[e];
            int idx = atomicAdd(&pos[r >> 6], 1);
            bcolval[idx] = make_int2(ecol[e] | ((r & 63) << 20), __float_as_int(eval[e]));
        }
    } else {
        // ---- gemm1: support1(bf16) = x(f32) @ W1; no LDS, no barriers ----
        const int tid = threadIdx.x;
        const int lane = tid & 63;
        const int w = tid >> 6;
        const int quad = lane >> 4;
        const int m = lane & 15;
        const int row0 = (blockIdx.x - NPART) * 128 + w * 32;

        int rA = row0 + m;
        int rB = row0 + 16 + m;
        rA = rA < NN ? rA : NN - 1;  // clamp loads; stores guarded
        rB = rB < NN ? rB : NN - 1;
        const float* pA = x + (size_t)rA * FIN + quad * 8;
        const float* pB = x + (size_t)rB * FIN + quad * 8;

        f32x4 acc[2][8];
#pragma unroll
        for (int i = 0; i < 2; ++i)
#pragma unroll
            for (int nt = 0; nt < 8; ++nt) acc[i][nt] = (f32x4){0.f, 0.f, 0.f, 0.f};

        float4 a0 = *(const float4*)pA;
        float4 a1 = *(const float4*)(pA + 4);
        float4 b0 = *(const float4*)pB;
        float4 b1 = *(const float4*)(pB + 4);

        for (int ks = 0; ks < 16; ++ks) {
            const int kn = (ks + 1) & 15;  // last-iter prefetch wraps (discarded)
            float4 na0 = *(const float4*)(pA + kn * 32);
            float4 na1 = *(const float4*)(pA + kn * 32 + 4);
            float4 nb0 = *(const float4*)(pB + kn * 32);
            float4 nb1 = *(const float4*)(pB + kn * 32 + 4);

            bf16x8 fA = pack8(a0, a1);
            bf16x8 fB = pack8(b0, b1);
            bf16x8 bb[8];
#pragma unroll
            for (int nt = 0; nt < 8; ++nt)
                bb[nt] = *(const bf16x8*)(W1t + ((size_t)((nt * 16 + ks) * 64 + lane)) * 8);
#pragma unroll
            for (int nt = 0; nt < 8; ++nt) {
                acc[0][nt] = __builtin_amdgcn_mfma_f32_16x16x32_bf16(fA, bb[nt], acc[0][nt], 0, 0, 0);
                acc[1][nt] = __builtin_amdgcn_mfma_f32_16x16x32_bf16(fB, bb[nt], acc[1][nt], 0, 0, 0);
            }
            a0 = na0; a1 = na1; b0 = nb0; b1 = nb1;
        }

#pragma unroll
        for (int i = 0; i < 2; ++i)
#pragma unroll
            for (int nt = 0; nt < 8; ++nt) {
                int col = nt * 16 + m;
#pragma unroll
                for (int r = 0; r < 4; ++r) {
                    int row = row0 + i * 16 + quad * 4 + r;
                    if (row < NN) outd[(size_t)row * FHID + col] = f2bf(acc[i][nt][r]);
                }
            }
    }
}

// ---------------- bucket_to_csr: 64-row buckets ----------------
__global__ __launch_bounds__(256) void bucket_to_csr(const int* __restrict__ off,
                                                     const int2* __restrict__ bcolval,
                                                     int* __restrict__ rowptr,
                                                     int2* __restrict__ epack) {
    __shared__ int cnt[BROWS];
    __shared__ int pos[BROWS];
    __shared__ int s[BROWS];
    __shared__ int2 eb[EBCAP];
    const int b = blockIdx.x;
    const int t = threadIdx.x;
    const int s0 = off[b * NPART];
    const int send = (b == NBUCK - 1) ? NE : off[(b + 1) * NPART];
    const int n = send - s0;
    const bool fits = (n <= EBCAP);
    if (t < BROWS) cnt[t] = 0;
    __syncthreads();
    int2 myv[10];
    if (fits) {
#pragma unroll
        for (int ii = 0; ii < 10; ++ii) {
            int i = t + ii * 256;
            int2 v = make_int2(0, 0);
            if (i < n) {
                v = bcolval[s0 + i];
                atomicAdd(&cnt[((unsigned)v.x) >> 20], 1);
            }
            myv[ii] = v;
        }
    } else {
        for (int i = t; i < n; i += 256)
            atomicAdd(&cnt[((unsigned)bcolval[s0 + i].x) >> 20], 1);
    }
    __syncthreads();
    int myc = (t < BROWS) ? cnt[t] : 0;
    if (t < BROWS) s[t] = myc;
    __syncthreads();
    for (int o = 1; o < BROWS; o <<= 1) {
        int xv = (t >= o && t < BROWS) ? s[t - o] : 0;
        __syncthreads();
        if (t < BROWS) s[t] += xv;
        __syncthreads();
    }
    if (t < BROWS) {
        int excl = s[t] - myc;
        pos[t] = excl;  // bucket-relative
        int row = b * BROWS + t;
        if (row < NN) rowptr[row] = s0 + excl;
    }
    if (b == 0 && t == 0) rowptr[NN] = NE;
    __syncthreads();
    if (fits) {
#pragma unroll
        for (int ii = 0; ii < 10; ++ii) {
            int i = t + ii * 256;
            if (i < n) {
                int2 v = myv[ii];
                int p = atomicAdd(&pos[((unsigned)v.x) >> 20], 1);
                eb[p] = make_int2(v.x & 0xFFFFF, v.y);
            }
        }
        __syncthreads();
        for (int i = t; i < n; i += 256) epack[s0 + i] = eb[i];
    } else {
        for (int i = t; i < n; i += 256) {
            int2 v = bcolval[s0 + i];
            int p = atomicAdd(&pos[((unsigned)v.x) >> 20], 1);
            epack[s0 + p] = make_int2(v.x & 0xFFFFF, v.y);
        }
    }
}

// ---------------- SpMM1 + bias + relu: h(bf16) = relu(A @ support1 + b1) ----------------
// Wave-per-row; descriptors via v_readlane (scalar path). 32-edge unrolled
// full chunks (32 gathers = 8KB in flight/wave, zero per-edge selects),
// 16-chunk + guarded tail.
__global__ __launch_bounds__(256) void spmm1_kernel(const int* __restrict__ rowptr,
                                                    const int2* __restrict__ epack,
                                                    const unsigned short* __restrict__ dense,
                                                    const float* __restrict__ b1,
                                                    unsigned short* __restrict__ h) {
    const int lane = threadIdx.x & 63;
    const int row = blockIdx.x * 4 + (threadIdx.x >> 6);
    const int start = __builtin_amdgcn_readfirstlane(rowptr[row]);
    const int cnt = __builtin_amdgcn_readfirstlane(rowptr[row + 1]) - start;
    const int sl16 = lane & 15;
    const unsigned* d32 = (const unsigned*)dense;
    float acc0 = 0.f, acc1 = 0.f;

    int j = 0;
    for (; j + 32 <= cnt; j += 32) {
        int2 p0 = epack[start + j + sl16];
        int2 p1 = epack[start + j + 16 + sl16];
        unsigned d[32];
#pragma unroll
        for (int k = 0; k < 16; ++k) {
            int c = __builtin_amdgcn_readlane(p0.x, k);
            d[k] = d32[((size_t)c << 6) + lane];
        }
#pragma unroll
        for (int k = 0; k < 16; ++k) {
            int c = __builtin_amdgcn_readlane(p1.x, k);
            d[16 + k] = d32[((size_t)c << 6) + lane];
        }
#pragma unroll
        for (int k = 0; k < 16; ++k) {
            float v = __int_as_float(__builtin_amdgcn_readlane(p0.y, k));
            acc0 = fmaf(v, bflo(d[k]), acc0);
            acc1 = fmaf(v, bfhi(d[k]), acc1);
        }
#pragma unroll
        for (int k = 0; k < 16; ++k) {
            float v = __int_as_float(__builtin_amdgcn_readlane(p1.y, k));
            acc0 = fmaf(v, bflo(d[16 + k]), acc0);
            acc1 = fmaf(v, bfhi(d[16 + k]), acc1);
        }
    }
    if (j + 16 <= cnt) {
        int2 p = epack[start + j + sl16];
        unsigned d[16];
#pragma unroll
        for (int k = 0; k < 16; ++k) {
            int c = __builtin_amdgcn_readlane(p.x, k);
            d[k] = d32[((size_t)c << 6) + lane];
        }
#pragma unroll
        for (int k = 0; k < 16; ++k) {
            float v = __int_as_float(__builtin_amdgcn_readlane(p.y, k));
            acc0 = fmaf(v, bflo(d[k]), acc0);
            acc1 = fmaf(v, bfhi(d[k]), acc1);
        }
        j += 16;
    }
    const int rem = cnt - j;
    if (rem > 0) {
        int idx = j + (sl16 < rem ? sl16 : rem - 1);
        int2 p = epack[start + idx];
        unsigned d[16];
#pragma unroll
        for (int k = 0; k < 16; ++k) {
            int c = __builtin_amdgcn_readlane(p.x, k);
            c = (k < rem) ? c : 0;
            d[k] = d32[((size_t)c << 6) + lane];
        }
#pragma unroll
        for (int k = 0; k < 16; ++k) {
            float v = (k < rem) ? __int_as_float(__builtin_amdgcn_readlane(p.y, k)) : 0.f;
            acc0 = fmaf(v, bflo(d[k]), acc0);
            acc1 = fmaf(v, bfhi(d[k]), acc1);
        }
    }
    float2 bb = *(const float2*)(b1 + lane * 2);
    unsigned r0 = f2bf(fmaxf(acc0 + bb.x, 0.f));
    unsigned r1 = f2bf(fmaxf(acc1 + bb.y, 0.f));
    *((unsigned*)(h + (size_t)row * FHID) + lane) = r0 | (r1 << 16);
}

// ---------------- GEMM2: support2(bf16) = h(bf16) @ W2(f32) ----------------
__global__ __launch_bounds__(256) void gemm2_kernel(const unsigned short* __restrict__ h,
                                                    const float* __restrict__ W2,
                                                    unsigned short* __restrict__ out) {
    __shared__ float hs[64][129];
    const int tid = threadIdx.x;
    const int lane = tid & 63;
    const int cg = __builtin_amdgcn_readfirstlane(tid >> 6);
    const int row0 = blockIdx.x * 64;
    const int row = row0 + lane;

    float acc[8];
#pragma unroll
    for (int c = 0; c < 8; ++c) acc[c] = 0.f;

#pragma unroll
    for (int j = 0; j < 8; ++j) {
        int f4 = tid + j * 256;
        int r = f4 >> 5;
        int kq = f4 & 31;
        ushort4 v = make_ushort4(0, 0, 0, 0);
        if (row0 + r < NN) v = *(const ushort4*)(h + (size_t)(row0 + r) * FHID + kq * 4);
        hs[r][kq * 4 + 0] = bf2f(v.x);
        hs[r][kq * 4 + 1] = bf2f(v.y);
        hs[r][kq * 4 + 2] = bf2f(v.z);
        hs[r][kq * 4 + 3] = bf2f(v.w);
    }
    __syncthreads();
#pragma unroll 4
    for (int k = 0; k < FHID; ++k) {
        float a = hs[lane][k];
        const float* wrow = W2 + k * FOUT + cg * 8;
#pragma unroll
        for (int c = 0; c < 8; ++c) acc[c] += a * wrow[c];
    }
    if (row < NN) {
        uint4 st;
        st.x = (unsigned)f2bf(acc[0]) | ((unsigned)f2bf(acc[1]) << 16);
        st.y = (unsigned)f2bf(acc[2]) | ((unsigned)f2bf(acc[3]) << 16);
        st.z = (unsigned)f2bf(acc[4]) | ((unsigned)f2bf(acc[5]) << 16);
        st.w = (unsigned)f2bf(acc[6]) | ((unsigned)f2bf(acc[7]) << 16);
        *(uint4*)(out + (size_t)row * FOUT + cg * 8) = st;
    }
}

// ------- SpMM2 + bias + log_softmax (fp32 out) -------
// Wave-per-row; quad q handles edges q*4..q*4+3 of each 16-edge chunk with
// dword gathers (lane covers cols 2*sl16, 2*sl16+1); quad partials combined
// by shfl_xor(16/32) before the softmax reduction.
__global__ __launch_bounds__(256) void spmm2_kernel(const int* __restrict__ rowptr,
                                                    const int2* __restrict__ epack,
                                                    const unsigned short* __restrict__ dense,
                                                    const float* __restrict__ b2,
                                                    float* __restrict__ out) {
    const int lane = threadIdx.x & 63;
    const int row = blockIdx.x * 4 + (threadIdx.x >> 6);
    const int start = __builtin_amdgcn_readfirstlane(rowptr[row]);
    const int cnt = __builtin_amdgcn_readfirstlane(rowptr[row + 1]) - start;
    const int quad = lane >> 4;
    const int sl16 = lane & 15;
    const unsigned* d32 = (const unsigned*)dense;
    float acc0 = 0.f, acc1 = 0.f;

    int j = 0;
    for (; j + 16 <= cnt; j += 16) {
        int2 p = epack[start + j + sl16];
        unsigned d[4];
        float vv[4];
#pragma unroll
        for (int k = 0; k < 16; ++k) {
            int c = __builtin_amdgcn_readlane(p.x, k);
            int v = __builtin_amdgcn_readlane(p.y, k);
            if ((k >> 2) == quad) {
                d[k & 3] = d32[((size_t)c << 4) + sl16];
                vv[k & 3] = __int_as_float(v);
            }
        }
#pragma unroll
        for (int k = 0; k < 4; ++k) {
            acc0 = fmaf(vv[k], bflo(d[k]), acc0);
            acc1 = fmaf(vv[k], bfhi(d[k]), acc1);
        }
    }
    const int rem = cnt - j;
    if (rem > 0) {
        int idx = j + (sl16 < rem ? sl16 : rem - 1);
        int2 p = epack[start + idx];
        unsigned d[4];
        float vv[4];
#pragma unroll
        for (int k = 0; k < 4; ++k) { d[k] = 0; vv[k] = 0.f; }
#pragma unroll
        for (int k = 0; k < 16; ++k) {
            int c = __builtin_amdgcn_readlane(p.x, k);
            int v = __builtin_amdgcn_readlane(p.y, k);
            c = (k < rem) ? c : 0;
            if ((k >> 2) == quad) {
                d[k & 3] = d32[((size_t)c << 4) + sl16];
                vv[k & 3] = (k < rem) ? __int_as_float(v) : 0.f;
            }
        }
#pragma unroll
        for (int k = 0; k < 4; ++k) {
            acc0 = fmaf(vv[k], bflo(d[k]), acc0);
            acc1 = fmaf(vv[k], bfhi(d[k]), acc1);
        }
    }
    // combine quad partials: all lanes end with totals for cols 2*sl16(+1)
    acc0 += __shfl_xor(acc0, 16, 64);
    acc0 += __shfl_xor(acc0, 32, 64);
    acc1 += __shfl_xor(acc1, 16, 64);
    acc1 += __shfl_xor(acc1, 32, 64);
    float2 bb = *(const float2*)(b2 + sl16 * 2);
    acc0 += bb.x;
    acc1 += bb.y;
    float m = fmaxf(acc0, acc1);
#pragma unroll
    for (int mask = 8; mask >= 1; mask >>= 1) m = fmaxf(m, __shfl_xor(m, mask, 64));
    float ssum = expf(acc0 - m) + expf(acc1 - m);
#pragma unroll
    for (int mask = 8; mask >= 1; mask >>= 1) ssum += __shfl_xor(ssum, mask, 64);
    float lse = m + logf(ssum);
    if (lane < 16) {
        float2 st = make_float2(acc0 - lse, acc1 - lse);
        *(float2*)(out + (size_t)row * FOUT + sl16 * 2) = st;
    }
}

extern "C" void kernel_launch(void* const* d_in, const int* in_sizes, int n_in,
                              void* d_out, int out_size, void* d_ws, size_t ws_size,
                              hipStream_t stream) {
    const float* x = (const float*)d_in[0];
    const int* erow = (const int*)d_in[1];
    const int* ecol = (const int*)d_in[2];
    const float* eval = (const float*)d_in[3];
    const float* W1 = (const float*)d_in[4];
    const float* b1 = (const float*)d_in[5];
    const float* W2 = (const float*)d_in[6];
    const float* b2 = (const float*)d_in[7];
    float* out = (float*)d_out;

    char* ws = (char*)d_ws;
    size_t off_b = 0;
    auto walloc = [&](size_t bytes) -> void* {
        void* p = ws + off_b;
        off_b = (off_b + bytes + 255) & ~(size_t)255;
        return p;
    };
    int2* epack = (int2*)walloc((size_t)NE * 8);
    int* rowptr = (int*)walloc((size_t)(NN + 1) * 4);
    int* cntG = (int*)walloc((size_t)TOT * 4);
    int* off = (int*)walloc((size_t)TOT * 4);
    int* partials = (int*)walloc(4096);
    unsigned short* W1t = (unsigned short*)walloc((size_t)FHID * FIN * 2);
    int2* bcolval = (int2*)walloc((size_t)NE * 8);
    unsigned short* support1 = (unsigned short*)walloc((size_t)NN * FHID * 2);
    unsigned short* h = (unsigned short*)walloc((size_t)NN * FHID * 2);
    unsigned short* support2 = support1;  // support1 dead after spmm1

    fused_prep_hist<<<NPART + 256, 256, 0, stream>>>(W1, W1t, erow, cntG);
    scan1_kernel<<<NSCAN1, 256, 0, stream>>>(cntG, off, partials);
    scan2_kernel<<<1, 512, 0, stream>>>(partials);
    scan3_kernel<<<NSCAN1, 256, 0, stream>>>(off, partials);
    fused_scatter_gemm1<<<NPART + GG1, 256, 0, stream>>>(erow, ecol, eval, off,
                                                         bcolval, x, W1t, support1);
    bucket_to_csr<<<NBUCK, 256, 0, stream>>>(off, bcolval, rowptr, epack);
    spmm1_kernel<<<NN / 4, 256, 0, stream>>>(rowptr, epack, support1, b1, h);
    gemm2_kernel<<<(NN + 63) / 64, 256, 0, stream>>>(h, W2, support2);
    spmm2_kernel<<<NN / 4, 256, 0, stream>>>(rowptr, epack, support2, b2, out);
}

// Round 5
// 606.400 us; speedup vs baseline: 1.0945x; 1.0630x over previous
//
#include <hip/hip_runtime.h>

// GCN forward on MI355X — bf16 intermediate pipeline.
//
// R9: R8 counters localized the straggler: scatter_part's loop interleaves
// coalesced loads with 64-way scattered 8B stores; FIFO vmcnt forces each
// iteration to drain the previous scattered store (64 line transactions)
// before its loads land => ~170us. Rewrite scatter as phase-separated
// LDS-staged radix scatter: A) load+hist (no stores), B) block scan,
// C) rank+scatter into LDS (100KB eb2), D) linear LDS->global sweep with
// run-coalesced wave stores (~8-16 transactions/wave vs 64). gemm1
// un-fused (R7 version). CHUNK = exact 12500.

#define NN 100000
#define NE 3200000
#define FIN 512
#define FHID 128
#define FOUT 32
#define BROWS 64             // rows per bucket
#define NBUCK 1563           // ceil(NN/64)
#define NPART 256            // scatter partitions
#define CHUNK 12500          // edges per partition; NPART*CHUNK == NE exactly
#define TOT (NBUCK * NPART)  // 400128 counter cells
#define NSCAN1 391           // ceil(TOT/1024)
#define EBCAP 2560           // bucket LDS staging capacity (E[n]=2048)
#define EPT 25               // edges per thread in scatter (ceil(12500/512))

typedef __attribute__((ext_vector_type(8))) short bf16x8;
typedef __attribute__((ext_vector_type(4))) float f32x4;

static __device__ __forceinline__ unsigned short f2bf(float f) {
    unsigned u = __float_as_uint(f);
    unsigned r = (u + 0x7FFFu + ((u >> 16) & 1u)) >> 16;  // RTN-even
    return (unsigned short)r;
}
static __device__ __forceinline__ float bf2f(unsigned short u) {
    return __uint_as_float(((unsigned)u) << 16);
}
static __device__ __forceinline__ float bflo(unsigned u) {
    return __uint_as_float(u << 16);
}
static __device__ __forceinline__ float bfhi(unsigned u) {
    return __uint_as_float(u & 0xffff0000u);
}
static __device__ __forceinline__ bf16x8 pack8(float4 u, float4 v) {
    bf16x8 r;
    r[0] = (short)f2bf(u.x); r[1] = (short)f2bf(u.y);
    r[2] = (short)f2bf(u.z); r[3] = (short)f2bf(u.w);
    r[4] = (short)f2bf(v.x); r[5] = (short)f2bf(v.y);
    r[6] = (short)f2bf(v.z); r[7] = (short)f2bf(v.w);
    return r;
}

// ---------------- CSR build phase 1: hist (+ fused W1 fragment-shuffle) ----------------
// W1t layout: 16B chunk c = (nt*16 + ks)*64 + lane; chunk holds bf16 of
// W1[ks*32 + (lane>>4)*8 + j][nt*16 + (lane&15)], j=0..7 -- the MFMA
// B-fragment wave order, so gemm1's B load is 16B/lane coalesced.
__global__ __launch_bounds__(256) void fused_prep_hist(const float* __restrict__ W1,
                                                       unsigned short* __restrict__ W1t,
                                                       const int* __restrict__ erow,
                                                       int* __restrict__ cntG) {
    if (blockIdx.x < NPART) {
        __shared__ int c[NBUCK];
        const int t = threadIdx.x;
        const int w = blockIdx.x;
        for (int i = t; i < NBUCK; i += 256) c[i] = 0;
        __syncthreads();
        const int e0 = w * CHUNK;
        const int e1 = min(e0 + CHUNK, NE);
        for (int e = e0 + t; e < e1; e += 256) atomicAdd(&c[erow[e] >> 6], 1);
        __syncthreads();
        for (int i = t; i < NBUCK; i += 256) cntG[w * NBUCK + i] = c[i];
    } else {
        int t = (blockIdx.x - NPART) * 256 + threadIdx.x;  // 65536 threads
        int j = t & 7;
        int c = t >> 3;
        int l = c & 63;
        int ks = (c >> 6) & 15;
        int nt = c >> 10;
        int n = nt * 16 + (l & 15);
        int k = ks * 32 + ((l >> 4) << 3) + j;
        W1t[(size_t)c * 8 + j] = f2bf(W1[k * FHID + n]);
    }
}

__global__ __launch_bounds__(256) void scan1_kernel(const int* __restrict__ cntG,
                                                    int* __restrict__ off,
                                                    int* __restrict__ partials) {
    __shared__ int s[256];
    int t = threadIdx.x;
    int i0 = blockIdx.x * 1024 + t * 4;
    int v[4];
#pragma unroll
    for (int j = 0; j < 4; ++j) {
        int i = i0 + j;
        // flat index i = b*NPART + w (bucket-major); cntG is [w][b]
        v[j] = (i < TOT) ? cntG[(i & (NPART - 1)) * NBUCK + (i >> 8)] : 0;
    }
    int lsum = v[0] + v[1] + v[2] + v[3];
    s[t] = lsum;
    __syncthreads();
    for (int o = 1; o < 256; o <<= 1) {
        int xv = (t >= o) ? s[t - o] : 0;
        __syncthreads();
        s[t] += xv;
        __syncthreads();
    }
    if (t == 255) partials[blockIdx.x] = s[255];
    int run = s[t] - lsum;
#pragma unroll
    for (int j = 0; j < 4; ++j) {
        if (i0 + j < TOT) off[i0 + j] = run;
        run += v[j];
    }
}

__global__ __launch_bounds__(512) void scan2_kernel(int* partials) {
    __shared__ int s[512];
    int t = threadIdx.x;
    int v = (t < NSCAN1) ? partials[t] : 0;
    s[t] = v;
    __syncthreads();
    for (int o = 1; o < 512; o <<= 1) {
        int xv = (t >= o) ? s[t - o] : 0;
        __syncthreads();
        s[t] += xv;
        __syncthreads();
    }
    if (t < NSCAN1) partials[t] = s[t] - v;
}

__global__ __launch_bounds__(256) void scan3_kernel(int* __restrict__ off,
                                                    const int* __restrict__ partials) {
    int add = partials[blockIdx.x];
    int i0 = blockIdx.x * 1024 + threadIdx.x * 4;
#pragma unroll
    for (int j = 0; j < 4; ++j)
        if (i0 + j < TOT) off[i0 + j] += add;
}

// ---------------- scatter_part: LDS-staged radix scatter ----------------
// Phases: A) load edges into regs + LDS hist (no global stores in loop);
// B) block scan of 1563 bucket counts; C) rank via LDS atomic + scatter
// records into LDS; D) linear LDS->global sweep: consecutive lanes write
// consecutive elements of each (bucket,partition) run => coalesced.
__global__ __launch_bounds__(512) void scatter_part(const int* __restrict__ erow,
                                                    const int* __restrict__ ecol,
                                                    const float* __restrict__ eval,
                                                    const int* __restrict__ off,
                                                    int2* __restrict__ bcolval) {
    __shared__ int2 eb2[CHUNK];            // 100000 B
    __shared__ unsigned short bkt2[CHUNK]; // 25000 B
    __shared__ int cnt[NBUCK];             // raw counts -> exclusive offsets
    __shared__ int pos[NBUCK];             // running cursors
    __shared__ int s[512];                 // block-scan workspace
    const int t = threadIdx.x;
    const int w = blockIdx.x;
    const int e0 = w * CHUNK;

    for (int i = t; i < NBUCK; i += 512) cnt[i] = 0;
    __syncthreads();

    // --- A: load + count ---
    int myb[EPT];
    int2 myrec[EPT];
#pragma unroll
    for (int ii = 0; ii < EPT; ++ii) {
        int i = t + ii * 512;
        myb[ii] = -1;
        if (i < CHUNK) {
            int e = e0 + i;
            int r = erow[e];
            int b = r >> 6;
            myb[ii] = b;
            myrec[ii] = make_int2(ecol[e] | ((r & 63) << 20), __float_as_int(eval[e]));
            atomicAdd(&cnt[b], 1);
        }
    }
    __syncthreads();

    // --- B: exclusive scan of cnt[0..NBUCK) in place ---
    int base = t * 4;
    int v[4];
#pragma unroll
    for (int j = 0; j < 4; ++j) v[j] = (base + j < NBUCK) ? cnt[base + j] : 0;
    int lsum = v[0] + v[1] + v[2] + v[3];
    s[t] = lsum;
    __syncthreads();
    for (int o = 1; o < 512; o <<= 1) {
        int xv = (t >= o) ? s[t - o] : 0;
        __syncthreads();
        s[t] += xv;
        __syncthreads();
    }
    int run = s[t] - lsum;
#pragma unroll
    for (int j = 0; j < 4; ++j) {
        if (base + j < NBUCK) cnt[base + j] = run;
        run += v[j];
    }
    __syncthreads();
    for (int i = t; i < NBUCK; i += 512) pos[i] = cnt[i];
    __syncthreads();

    // --- C: rank + LDS scatter ---
#pragma unroll
    for (int ii = 0; ii < EPT; ++ii) {
        if (myb[ii] >= 0) {
            int ld = atomicAdd(&pos[myb[ii]], 1);
            eb2[ld] = myrec[ii];
            bkt2[ld] = (unsigned short)myb[ii];
        }
    }
    __syncthreads();

    // --- D: coalesced global write (runs) ---
    for (int i = t; i < CHUNK; i += 512) {
        int2 rec = eb2[i];
        int b = bkt2[i];
        int dest = off[b * NPART + w] + (i - cnt[b]);
        bcolval[dest] = rec;
    }
}

// ---------------- bucket_to_csr: 64-row buckets ----------------
__global__ __launch_bounds__(256) void bucket_to_csr(const int* __restrict__ off,
                                                     const int2* __restrict__ bcolval,
                                                     int* __restrict__ rowptr,
                                                     int2* __restrict__ epack) {
    __shared__ int cnt[BROWS];
    __shared__ int pos[BROWS];
    __shared__ int s[BROWS];
    __shared__ int2 eb[EBCAP];
    const int b = blockIdx.x;
    const int t = threadIdx.x;
    const int s0 = off[b * NPART];
    const int send = (b == NBUCK - 1) ? NE : off[(b + 1) * NPART];
    const int n = send - s0;
    const bool fits = (n <= EBCAP);
    if (t < BROWS) cnt[t] = 0;
    __syncthreads();
    int2 myv[10];
    if (fits) {
#pragma unroll
        for (int ii = 0; ii < 10; ++ii) {
            int i = t + ii * 256;
            int2 v = make_int2(0, 0);
            if (i < n) {
                v = bcolval[s0 + i];
                atomicAdd(&cnt[((unsigned)v.x) >> 20], 1);
            }
            myv[ii] = v;
        }
    } else {
        for (int i = t; i < n; i += 256)
            atomicAdd(&cnt[((unsigned)bcolval[s0 + i].x) >> 20], 1);
    }
    __syncthreads();
    int myc = (t < BROWS) ? cnt[t] : 0;
    if (t < BROWS) s[t] = myc;
    __syncthreads();
    for (int o = 1; o < BROWS; o <<= 1) {
        int xv = (t >= o && t < BROWS) ? s[t - o] : 0;
        __syncthreads();
        if (t < BROWS) s[t] += xv;
        __syncthreads();
    }
    if (t < BROWS) {
        int excl = s[t] - myc;
        pos[t] = excl;  // bucket-relative
        int row = b * BROWS + t;
        if (row < NN) rowptr[row] = s0 + excl;
    }
    if (b == 0 && t == 0) rowptr[NN] = NE;
    __syncthreads();
    if (fits) {
#pragma unroll
        for (int ii = 0; ii < 10; ++ii) {
            int i = t + ii * 256;
            if (i < n) {
                int2 v = myv[ii];
                int p = atomicAdd(&pos[((unsigned)v.x) >> 20], 1);
                eb[p] = make_int2(v.x & 0xFFFFF, v.y);
            }
        }
        __syncthreads();
        for (int i = t; i < n; i += 256) epack[s0 + i] = eb[i];
    } else {
        for (int i = t; i < n; i += 256) {
            int2 v = bcolval[s0 + i];
            int p = atomicAdd(&pos[((unsigned)v.x) >> 20], 1);
            epack[s0 + p] = make_int2(v.x & 0xFFFFF, v.y);
        }
    }
}

// ---------------- GEMM1 (MFMA, no LDS): support1(bf16) = x(f32) @ W1 ----------------
__global__ __launch_bounds__(256) void gemm1_mfma(const float* __restrict__ x,
                                                  const unsigned short* __restrict__ W1t,
                                                  unsigned short* __restrict__ out) {
    const int tid = threadIdx.x;
    const int lane = tid & 63;
    const int w = tid >> 6;
    const int quad = lane >> 4;
    const int m = lane & 15;
    const int row0 = blockIdx.x * 128 + w * 32;

    int rA = row0 + m;
    int rB = row0 + 16 + m;
    rA = rA < NN ? rA : NN - 1;  // clamp loads; stores guarded
    rB = rB < NN ? rB : NN - 1;
    const float* pA = x + (size_t)rA * FIN + quad * 8;
    const float* pB = x + (size_t)rB * FIN + quad * 8;

    f32x4 acc[2][8];
#pragma unroll
    for (int i = 0; i < 2; ++i)
#pragma unroll
        for (int nt = 0; nt < 8; ++nt) acc[i][nt] = (f32x4){0.f, 0.f, 0.f, 0.f};

    float4 a0 = *(const float4*)pA;
    float4 a1 = *(const float4*)(pA + 4);
    float4 b0 = *(const float4*)pB;
    float4 b1 = *(const float4*)(pB + 4);

    for (int ks = 0; ks < 16; ++ks) {
        const int kn = (ks + 1) & 15;  // last-iter prefetch wraps (discarded)
        float4 na0 = *(const float4*)(pA + kn * 32);
        float4 na1 = *(const float4*)(pA + kn * 32 + 4);
        float4 nb0 = *(const float4*)(pB + kn * 32);
        float4 nb1 = *(const float4*)(pB + kn * 32 + 4);

        bf16x8 fA = pack8(a0, a1);
        bf16x8 fB = pack8(b0, b1);
        bf16x8 bb[8];
#pragma unroll
        for (int nt = 0; nt < 8; ++nt)
            bb[nt] = *(const bf16x8*)(W1t + ((size_t)((nt * 16 + ks) * 64 + lane)) * 8);
#pragma unroll
        for (int nt = 0; nt < 8; ++nt) {
            acc[0][nt] = __builtin_amdgcn_mfma_f32_16x16x32_bf16(fA, bb[nt], acc[0][nt], 0, 0, 0);
            acc[1][nt] = __builtin_amdgcn_mfma_f32_16x16x32_bf16(fB, bb[nt], acc[1][nt], 0, 0, 0);
        }
        a0 = na0; a1 = na1; b0 = nb0; b1 = nb1;
    }

#pragma unroll
    for (int i = 0; i < 2; ++i)
#pragma unroll
        for (int nt = 0; nt < 8; ++nt) {
            int col = nt * 16 + m;
#pragma unroll
            for (int r = 0; r < 4; ++r) {
                int row = row0 + i * 16 + quad * 4 + r;
                if (row < NN) out[(size_t)row * FHID + col] = f2bf(acc[i][nt][r]);
            }
        }
}

// ---------------- SpMM1 + bias + relu: h(bf16) = relu(A @ support1 + b1) ----------------
// Wave-per-row; descriptors via v_readlane (scalar path). 32-edge unrolled
// full chunks (32 gathers = 8KB in flight/wave), 16-chunk + guarded tail.
__global__ __launch_bounds__(256) void spmm1_kernel(const int* __restrict__ rowptr,
                                                    const int2* __restrict__ epack,
                                                    const unsigned short* __restrict__ dense,
                                                    const float* __restrict__ b1,
                                                    unsigned short* __restrict__ h) {
    const int lane = threadIdx.x & 63;
    const int row = blockIdx.x * 4 + (threadIdx.x >> 6);
    const int start = __builtin_amdgcn_readfirstlane(rowptr[row]);
    const int cnt = __builtin_amdgcn_readfirstlane(rowptr[row + 1]) - start;
    const int sl16 = lane & 15;
    const unsigned* d32 = (const unsigned*)dense;
    float acc0 = 0.f, acc1 = 0.f;

    int j = 0;
    for (; j + 32 <= cnt; j += 32) {
        int2 p0 = epack[start + j + sl16];
        int2 p1 = epack[start + j + 16 + sl16];
        unsigned d[32];
#pragma unroll
        for (int k = 0; k < 16; ++k) {
            int c = __builtin_amdgcn_readlane(p0.x, k);
            d[k] = d32[((size_t)c << 6) + lane];
        }
#pragma unroll
        for (int k = 0; k < 16; ++k) {
            int c = __builtin_amdgcn_readlane(p1.x, k);
            d[16 + k] = d32[((size_t)c << 6) + lane];
        }
#pragma unroll
        for (int k = 0; k < 16; ++k) {
            float v = __int_as_float(__builtin_amdgcn_readlane(p0.y, k));
            acc0 = fmaf(v, bflo(d[k]), acc0);
            acc1 = fmaf(v, bfhi(d[k]), acc1);
        }
#pragma unroll
        for (int k = 0; k < 16; ++k) {
            float v = __int_as_float(__builtin_amdgcn_readlane(p1.y, k));
            acc0 = fmaf(v, bflo(d[16 + k]), acc0);
            acc1 = fmaf(v, bfhi(d[16 + k]), acc1);
        }
    }
    if (j + 16 <= cnt) {
        int2 p = epack[start + j + sl16];
        unsigned d[16];
#pragma unroll
        for (int k = 0; k < 16; ++k) {
            int c = __builtin_amdgcn_readlane(p.x, k);
            d[k] = d32[((size_t)c << 6) + lane];
        }
#pragma unroll
        for (int k = 0; k < 16; ++k) {
            float v = __int_as_float(__builtin_amdgcn_readlane(p.y, k));
            acc0 = fmaf(v, bflo(d[k]), acc0);
            acc1 = fmaf(v, bfhi(d[k]), acc1);
        }
        j += 16;
    }
    const int rem = cnt - j;
    if (rem > 0) {
        int idx = j + (sl16 < rem ? sl16 : rem - 1);
        int2 p = epack[start + idx];
        unsigned d[16];
#pragma unroll
        for (int k = 0; k < 16; ++k) {
            int c = __builtin_amdgcn_readlane(p.x, k);
            c = (k < rem) ? c : 0;
            d[k] = d32[((size_t)c << 6) + lane];
        }
#pragma unroll
        for (int k = 0; k < 16; ++k) {
            float v = (k < rem) ? __int_as_float(__builtin_amdgcn_readlane(p.y, k)) : 0.f;
            acc0 = fmaf(v, bflo(d[k]), acc0);
            acc1 = fmaf(v, bfhi(d[k]), acc1);
        }
    }
    float2 bb = *(const float2*)(b1 + lane * 2);
    unsigned r0 = f2bf(fmaxf(acc0 + bb.x, 0.f));
    unsigned r1 = f2bf(fmaxf(acc1 + bb.y, 0.f));
    *((unsigned*)(h + (size_t)row * FHID) + lane) = r0 | (r1 << 16);
}

// ---------------- GEMM2: support2(bf16) = h(bf16) @ W2(f32) ----------------
__global__ __launch_bounds__(256) void gemm2_kernel(const unsigned short* __restrict__ h,
                                                    const float* __restrict__ W2,
                                                    unsigned short* __restrict__ out) {
    __shared__ float hs[64][129];
    const int tid = threadIdx.x;
    const int lane = tid & 63;
    const int cg = __builtin_amdgcn_readfirstlane(tid >> 6);
    const int row0 = blockIdx.x * 64;
    const int row = row0 + lane;

    float acc[8];
#pragma unroll
    for (int c = 0; c < 8; ++c) acc[c] = 0.f;

#pragma unroll
    for (int j = 0; j < 8; ++j) {
        int f4 = tid + j * 256;
        int r = f4 >> 5;
        int kq = f4 & 31;
        ushort4 v = make_ushort4(0, 0, 0, 0);
        if (row0 + r < NN) v = *(const ushort4*)(h + (size_t)(row0 + r) * FHID + kq * 4);
        hs[r][kq * 4 + 0] = bf2f(v.x);
        hs[r][kq * 4 + 1] = bf2f(v.y);
        hs[r][kq * 4 + 2] = bf2f(v.z);
        hs[r][kq * 4 + 3] = bf2f(v.w);
    }
    __syncthreads();
#pragma unroll 4
    for (int k = 0; k < FHID; ++k) {
        float a = hs[lane][k];
        const float* wrow = W2 + k * FOUT + cg * 8;
#pragma unroll
        for (int c = 0; c < 8; ++c) acc[c] += a * wrow[c];
    }
    if (row < NN) {
        uint4 st;
        st.x = (unsigned)f2bf(acc[0]) | ((unsigned)f2bf(acc[1]) << 16);
        st.y = (unsigned)f2bf(acc[2]) | ((unsigned)f2bf(acc[3]) << 16);
        st.z = (unsigned)f2bf(acc[4]) | ((unsigned)f2bf(acc[5]) << 16);
        st.w = (unsigned)f2bf(acc[6]) | ((unsigned)f2bf(acc[7]) << 16);
        *(uint4*)(out + (size_t)row * FOUT + cg * 8) = st;
    }
}

// ------- SpMM2 + bias + log_softmax (fp32 out) -------
__global__ __launch_bounds__(256) void spmm2_kernel(const int* __restrict__ rowptr,
                                                    const int2* __restrict__ epack,
                                                    const unsigned short* __restrict__ dense,
                                                    const float* __restrict__ b2,
                                                    float* __restrict__ out) {
    const int lane = threadIdx.x & 63;
    const int row = blockIdx.x * 4 + (threadIdx.x >> 6);
    const int start = __builtin_amdgcn_readfirstlane(rowptr[row]);
    const int cnt = __builtin_amdgcn_readfirstlane(rowptr[row + 1]) - start;
    const int quad = lane >> 4;
    const int sl16 = lane & 15;
    const unsigned* d32 = (const unsigned*)dense;
    float acc0 = 0.f, acc1 = 0.f;

    int j = 0;
    for (; j + 16 <= cnt; j += 16) {
        int2 p = epack[start + j + sl16];
        unsigned d[4];
        float vv[4];
#pragma unroll
        for (int k = 0; k < 16; ++k) {
            int c = __builtin_amdgcn_readlane(p.x, k);
            int v = __builtin_amdgcn_readlane(p.y, k);
            if ((k >> 2) == quad) {
                d[k & 3] = d32[((size_t)c << 4) + sl16];
                vv[k & 3] = __int_as_float(v);
            }
        }
#pragma unroll
        for (int k = 0; k < 4; ++k) {
            acc0 = fmaf(vv[k], bflo(d[k]), acc0);
            acc1 = fmaf(vv[k], bfhi(d[k]), acc1);
        }
    }
    const int rem = cnt - j;
    if (rem > 0) {
        int idx = j + (sl16 < rem ? sl16 : rem - 1);
        int2 p = epack[start + idx];
        unsigned d[4];
        float vv[4];
#pragma unroll
        for (int k = 0; k < 4; ++k) { d[k] = 0; vv[k] = 0.f; }
#pragma unroll
        for (int k = 0; k < 16; ++k) {
            int c = __builtin_amdgcn_readlane(p.x, k);
            int v = __builtin_amdgcn_readlane(p.y, k);
            c = (k < rem) ? c : 0;
            if ((k >> 2) == quad) {
                d[k & 3] = d32[((size_t)c << 4) + sl16];
                vv[k & 3] = (k < rem) ? __int_as_float(v) : 0.f;
            }
        }
#pragma unroll
        for (int k = 0; k < 4; ++k) {
            acc0 = fmaf(vv[k], bflo(d[k]), acc0);
            acc1 = fmaf(vv[k], bfhi(d[k]), acc1);
        }
    }
    // combine quad partials: all lanes end with totals for cols 2*sl16(+1)
    acc0 += __shfl_xor(acc0, 16, 64);
    acc0 += __shfl_xor(acc0, 32, 64);
    acc1 += __shfl_xor(acc1, 16, 64);
    acc1 += __shfl_xor(acc1, 32, 64);
    float2 bb = *(const float2*)(b2 + sl16 * 2);
    acc0 += bb.x;
    acc1 += bb.y;
    float m = fmaxf(acc0, acc1);
#pragma unroll
    for (int mask = 8; mask >= 1; mask >>= 1) m = fmaxf(m, __shfl_xor(m, mask, 64));
    float ssum = expf(acc0 - m) + expf(acc1 - m);
#pragma unroll
    for (int mask = 8; mask >= 1; mask >>= 1) ssum += __shfl_xor(ssum, mask, 64);
    float lse = m + logf(ssum);
    if (lane < 16) {
        float2 st = make_float2(acc0 - lse, acc1 - lse);
        *(float2*)(out + (size_t)row * FOUT + sl16 * 2) = st;
    }
}

extern "C" void kernel_launch(void* const* d_in, const int* in_sizes, int n_in,
                              void* d_out, int out_size, void* d_ws, size_t ws_size,
                              hipStream_t stream) {
    const float* x = (const float*)d_in[0];
    const int* erow = (const int*)d_in[1];
    const int* ecol = (const int*)d_in[2];
    const float* eval = (const float*)d_in[3];
    const float* W1 = (const float*)d_in[4];
    const float* b1 = (const float*)d_in[5];
    const float* W2 = (const float*)d_in[6];
    const float* b2 = (const float*)d_in[7];
    float* out = (float*)d_out;

    char* ws = (char*)d_ws;
    size_t off_b = 0;
    auto walloc = [&](size_t bytes) -> void* {
        void* p = ws + off_b;
        off_b = (off_b + bytes + 255) & ~(size_t)255;
        return p;
    };
    int2* epack = (int2*)walloc((size_t)NE * 8);
    int* rowptr = (int*)walloc((size_t)(NN + 1) * 4);
    int* cntG = (int*)walloc((size_t)TOT * 4);
    int* off = (int*)walloc((size_t)TOT * 4);
    int* partials = (int*)walloc(4096);
    unsigned short* W1t = (unsigned short*)walloc((size_t)FHID * FIN * 2);
    int2* bcolval = (int2*)walloc((size_t)NE * 8);
    unsigned short* support1 = (unsigned short*)walloc((size_t)NN * FHID * 2);
    unsigned short* h = (unsigned short*)walloc((size_t)NN * FHID * 2);
    unsigned short* support2 = support1;  // support1 dead after spmm1

    fused_prep_hist<<<NPART + 256, 256, 0, stream>>>(W1, W1t, erow, cntG);
    scan1_kernel<<<NSCAN1, 256, 0, stream>>>(cntG, off, partials);
    scan2_kernel<<<1, 512, 0, stream>>>(partials);
    scan3_kernel<<<NSCAN1, 256, 0, stream>>>(off, partials);
    scatter_part<<<NPART, 512, 0, stream>>>(erow, ecol, eval, off, bcolval);
    bucket_to_csr<<<NBUCK, 256, 0, stream>>>(off, bcolval, rowptr, epack);
    gemm1_mfma<<<(NN + 127) / 128, 256, 0, stream>>>(x, W1t, support1);
    spmm1_kernel<<<NN / 4, 256, 0, stream>>>(rowptr, epack, support1, b1, h);
    gemm2_kernel<<<(NN + 63) / 64, 256, 0, stream>>>(h, W2, support2);
    spmm2_kernel<<<NN / 4, 256, 0, stream>>>(rowptr, epack, support2, b2, out);
}

// Round 6
// 596.665 us; speedup vs baseline: 1.1124x; 1.0163x over previous
//
#include <hip/hip_runtime.h>

// GCN forward on MI355X — bf16 intermediate pipeline.
//
// R10: (1) gemm2 fused INTO spmm1 — wave ends holding the full h-row in
// regs (lane j: cols 2j,2j+1); support2 = h@W2 computed in-wave via
// v_readlane chunk broadcast + LDS-staged W2 (w2l[64j+lane], conflict-free);
// h never touches memory (−57MB, −1 kernel). (2) scan3 deleted: consumers
// add partials[idx>>10] directly. (3) bucket_to_csr ∥ gemm1 grid-fusion
// (R5-proven; 21KB summed LDS keeps ~7 blocks/CU; R8 lesson: branch LDS
// sums, so the 146KB scatter can't pair). 7 launches.

#define NN 100000
#define NE 3200000
#define FIN 512
#define FHID 128
#define FOUT 32
#define BROWS 64             // rows per bucket
#define NBUCK 1563           // ceil(NN/64)
#define NPART 256            // scatter partitions
#define CHUNK 12500          // edges per partition; NPART*CHUNK == NE exactly
#define TOT (NBUCK * NPART)  // 400128 counter cells
#define NSCAN1 391           // ceil(TOT/1024)
#define EBCAP 2560           // bucket LDS staging capacity (E[n]=2048)
#define EPT 25               // edges per thread in scatter (ceil(12500/512))
#define GG1 ((NN + 127) / 128)  // gemm1 blocks = 782

typedef __attribute__((ext_vector_type(8))) short bf16x8;
typedef __attribute__((ext_vector_type(4))) float f32x4;

static __device__ __forceinline__ unsigned short f2bf(float f) {
    unsigned u = __float_as_uint(f);
    unsigned r = (u + 0x7FFFu + ((u >> 16) & 1u)) >> 16;  // RTN-even
    return (unsigned short)r;
}
static __device__ __forceinline__ float bf2f(unsigned short u) {
    return __uint_as_float(((unsigned)u) << 16);
}
static __device__ __forceinline__ float bflo(unsigned u) {
    return __uint_as_float(u << 16);
}
static __device__ __forceinline__ float bfhi(unsigned u) {
    return __uint_as_float(u & 0xffff0000u);
}
static __device__ __forceinline__ bf16x8 pack8(float4 u, float4 v) {
    bf16x8 r;
    r[0] = (short)f2bf(u.x); r[1] = (short)f2bf(u.y);
    r[2] = (short)f2bf(u.z); r[3] = (short)f2bf(u.w);
    r[4] = (short)f2bf(v.x); r[5] = (short)f2bf(v.y);
    r[6] = (short)f2bf(v.z); r[7] = (short)f2bf(v.w);
    return r;
}

// ---------------- CSR build phase 1: hist (+ fused W1 fragment-shuffle) ----------------
__global__ __launch_bounds__(256) void fused_prep_hist(const float* __restrict__ W1,
                                                       unsigned short* __restrict__ W1t,
                                                       const int* __restrict__ erow,
                                                       int* __restrict__ cntG) {
    if (blockIdx.x < NPART) {
        __shared__ int c[NBUCK];
        const int t = threadIdx.x;
        const int w = blockIdx.x;
        for (int i = t; i < NBUCK; i += 256) c[i] = 0;
        __syncthreads();
        const int e0 = w * CHUNK;
        const int e1 = min(e0 + CHUNK, NE);
        for (int e = e0 + t; e < e1; e += 256) atomicAdd(&c[erow[e] >> 6], 1);
        __syncthreads();
        for (int i = t; i < NBUCK; i += 256) cntG[w * NBUCK + i] = c[i];
    } else {
        int t = (blockIdx.x - NPART) * 256 + threadIdx.x;  // 65536 threads
        int j = t & 7;
        int c = t >> 3;
        int l = c & 63;
        int ks = (c >> 6) & 15;
        int nt = c >> 10;
        int n = nt * 16 + (l & 15);
        int k = ks * 32 + ((l >> 4) << 3) + j;
        W1t[(size_t)c * 8 + j] = f2bf(W1[k * FHID + n]);
    }
}

__global__ __launch_bounds__(256) void scan1_kernel(const int* __restrict__ cntG,
                                                    int* __restrict__ off,
                                                    int* __restrict__ partials) {
    __shared__ int s[256];
    int t = threadIdx.x;
    int i0 = blockIdx.x * 1024 + t * 4;
    int v[4];
#pragma unroll
    for (int j = 0; j < 4; ++j) {
        int i = i0 + j;
        // flat index i = b*NPART + w (bucket-major); cntG is [w][b]
        v[j] = (i < TOT) ? cntG[(i & (NPART - 1)) * NBUCK + (i >> 8)] : 0;
    }
    int lsum = v[0] + v[1] + v[2] + v[3];
    s[t] = lsum;
    __syncthreads();
    for (int o = 1; o < 256; o <<= 1) {
        int xv = (t >= o) ? s[t - o] : 0;
        __syncthreads();
        s[t] += xv;
        __syncthreads();
    }
    if (t == 255) partials[blockIdx.x] = s[255];
    int run = s[t] - lsum;
#pragma unroll
    for (int j = 0; j < 4; ++j) {
        if (i0 + j < TOT) off[i0 + j] = run;
        run += v[j];
    }
}

__global__ __launch_bounds__(512) void scan2_kernel(int* partials) {
    __shared__ int s[512];
    int t = threadIdx.x;
    int v = (t < NSCAN1) ? partials[t] : 0;
    s[t] = v;
    __syncthreads();
    for (int o = 1; o < 512; o <<= 1) {
        int xv = (t >= o) ? s[t - o] : 0;
        __syncthreads();
        s[t] += xv;
        __syncthreads();
    }
    if (t < NSCAN1) partials[t] = s[t] - v;
}

// ---------------- scatter_part: LDS-staged radix scatter ----------------
// partials folded here (scan3 deleted): ofsG[b] = off[b*NPART+w] +
// partials[(b*NPART+w)>>10] cached in LDS for the phase-D sweep.
__global__ __launch_bounds__(512) void scatter_part(const int* __restrict__ erow,
                                                    const int* __restrict__ ecol,
                                                    const float* __restrict__ eval,
                                                    const int* __restrict__ off,
                                                    const int* __restrict__ partials,
                                                    int2* __restrict__ bcolval) {
    __shared__ int2 eb2[CHUNK];            // 100000 B
    __shared__ unsigned short bkt2[CHUNK]; // 25000 B
    __shared__ int cnt[NBUCK];             // raw counts -> exclusive offsets
    __shared__ int pos[NBUCK];             // running cursors
    __shared__ int ofsG[NBUCK];            // final global base per bucket
    __shared__ int s[512];                 // block-scan workspace
    const int t = threadIdx.x;
    const int w = blockIdx.x;
    const int e0 = w * CHUNK;

    for (int i = t; i < NBUCK; i += 512) cnt[i] = 0;
    __syncthreads();

    // --- A: load + count ---
    int myb[EPT];
    int2 myrec[EPT];
#pragma unroll
    for (int ii = 0; ii < EPT; ++ii) {
        int i = t + ii * 512;
        myb[ii] = -1;
        if (i < CHUNK) {
            int e = e0 + i;
            int r = erow[e];
            int b = r >> 6;
            myb[ii] = b;
            myrec[ii] = make_int2(ecol[e] | ((r & 63) << 20), __float_as_int(eval[e]));
            atomicAdd(&cnt[b], 1);
        }
    }
    __syncthreads();

    // --- B: exclusive scan of cnt[0..NBUCK) in place ---
    int base = t * 4;
    int v[4];
#pragma unroll
    for (int j = 0; j < 4; ++j) v[j] = (base + j < NBUCK) ? cnt[base + j] : 0;
    int lsum = v[0] + v[1] + v[2] + v[3];
    s[t] = lsum;
    __syncthreads();
    for (int o = 1; o < 512; o <<= 1) {
        int xv = (t >= o) ? s[t - o] : 0;
        __syncthreads();
        s[t] += xv;
        __syncthreads();
    }
    int run = s[t] - lsum;
#pragma unroll
    for (int j = 0; j < 4; ++j) {
        if (base + j < NBUCK) cnt[base + j] = run;
        run += v[j];
    }
    __syncthreads();
    for (int i = t; i < NBUCK; i += 512) {
        pos[i] = cnt[i];
        int fi = i * NPART + w;
        ofsG[i] = off[fi] + partials[fi >> 10];
    }
    __syncthreads();

    // --- C: rank + LDS scatter ---
#pragma unroll
    for (int ii = 0; ii < EPT; ++ii) {
        if (myb[ii] >= 0) {
            int ld = atomicAdd(&pos[myb[ii]], 1);
            eb2[ld] = myrec[ii];
            bkt2[ld] = (unsigned short)myb[ii];
        }
    }
    __syncthreads();

    // --- D: coalesced global write (runs) ---
    for (int i = t; i < CHUNK; i += 512) {
        int2 rec = eb2[i];
        int b = bkt2[i];
        int dest = ofsG[b] + (i - cnt[b]);
        bcolval[dest] = rec;
    }
}

// ---------------- Fused: bucket_to_csr (first) || gemm1 (MFMA, LDS-free) ----------------
__global__ __launch_bounds__(256) void fused_csr_gemm1(
    const int* __restrict__ off, const int* __restrict__ partials,
    const int2* __restrict__ bcolval, int* __restrict__ rowptr,
    int2* __restrict__ epack,
    const float* __restrict__ x, const unsigned short* __restrict__ W1t,
    unsigned short* __restrict__ outd) {
    __shared__ int cnt[BROWS];
    __shared__ int pos[BROWS];
    __shared__ int s[BROWS];
    __shared__ int2 eb[EBCAP];
    if (blockIdx.x < NBUCK) {
        // ---- bucket_to_csr ----
        const int b = blockIdx.x;
        const int t = threadIdx.x;
        const int fi = b * NPART;
        const int s0 = off[fi] + partials[fi >> 10];
        const int send = (b == NBUCK - 1)
                             ? NE
                             : off[fi + NPART] + partials[(fi + NPART) >> 10];
        const int n = send - s0;
        const bool fits = (n <= EBCAP);
        if (t < BROWS) cnt[t] = 0;
        __syncthreads();
        int2 myv[10];
        if (fits) {
#pragma unroll
            for (int ii = 0; ii < 10; ++ii) {
                int i = t + ii * 256;
                int2 v = make_int2(0, 0);
                if (i < n) {
                    v = bcolval[s0 + i];
                    atomicAdd(&cnt[((unsigned)v.x) >> 20], 1);
                }
                myv[ii] = v;
            }
        } else {
            for (int i = t; i < n; i += 256)
                atomicAdd(&cnt[((unsigned)bcolval[s0 + i].x) >> 20], 1);
        }
        __syncthreads();
        int myc = (t < BROWS) ? cnt[t] : 0;
        if (t < BROWS) s[t] = myc;
        __syncthreads();
        for (int o = 1; o < BROWS; o <<= 1) {
            int xv = (t >= o && t < BROWS) ? s[t - o] : 0;
            __syncthreads();
            if (t < BROWS) s[t] += xv;
            __syncthreads();
        }
        if (t < BROWS) {
            int excl = s[t] - myc;
            pos[t] = excl;  // bucket-relative
            int row = b * BROWS + t;
            if (row < NN) rowptr[row] = s0 + excl;
        }
        if (b == 0 && t == 0) rowptr[NN] = NE;
        __syncthreads();
        if (fits) {
#pragma unroll
            for (int ii = 0; ii < 10; ++ii) {
                int i = t + ii * 256;
                if (i < n) {
                    int2 v = myv[ii];
                    int p = atomicAdd(&pos[((unsigned)v.x) >> 20], 1);
                    eb[p] = make_int2(v.x & 0xFFFFF, v.y);
                }
            }
            __syncthreads();
            for (int i = t; i < n; i += 256) epack[s0 + i] = eb[i];
        } else {
            for (int i = t; i < n; i += 256) {
                int2 v = bcolval[s0 + i];
                int p = atomicAdd(&pos[((unsigned)v.x) >> 20], 1);
                epack[s0 + p] = make_int2(v.x & 0xFFFFF, v.y);
            }
        }
    } else {
        // ---- gemm1: support1(bf16) = x(f32) @ W1 ----
        const int tid = threadIdx.x;
        const int lane = tid & 63;
        const int w = tid >> 6;
        const int quad = lane >> 4;
        const int m = lane & 15;
        const int row0 = (blockIdx.x - NBUCK) * 128 + w * 32;

        int rA = row0 + m;
        int rB = row0 + 16 + m;
        rA = rA < NN ? rA : NN - 1;  // clamp loads; stores guarded
        rB = rB < NN ? rB : NN - 1;
        const float* pA = x + (size_t)rA * FIN + quad * 8;
        const float* pB = x + (size_t)rB * FIN + quad * 8;

        f32x4 acc[2][8];
#pragma unroll
        for (int i = 0; i < 2; ++i)
#pragma unroll
            for (int nt = 0; nt < 8; ++nt) acc[i][nt] = (f32x4){0.f, 0.f, 0.f, 0.f};

        float4 a0 = *(const float4*)pA;
        float4 a1 = *(const float4*)(pA + 4);
        float4 b0 = *(const float4*)pB;
        float4 b1 = *(const float4*)(pB + 4);

        for (int ks = 0; ks < 16; ++ks) {
            const int kn = (ks + 1) & 15;  // last-iter prefetch wraps (discarded)
            float4 na0 = *(const float4*)(pA + kn * 32);
            float4 na1 = *(const float4*)(pA + kn * 32 + 4);
            float4 nb0 = *(const float4*)(pB + kn * 32);
            float4 nb1 = *(const float4*)(pB + kn * 32 + 4);

            bf16x8 fA = pack8(a0, a1);
            bf16x8 fB = pack8(b0, b1);
            bf16x8 bb[8];
#pragma unroll
            for (int nt = 0; nt < 8; ++nt)
                bb[nt] = *(const bf16x8*)(W1t + ((size_t)((nt * 16 + ks) * 64 + lane)) * 8);
#pragma unroll
            for (int nt = 0; nt < 8; ++nt) {
                acc[0][nt] = __builtin_amdgcn_mfma_f32_16x16x32_bf16(fA, bb[nt], acc[0][nt], 0, 0, 0);
                acc[1][nt] = __builtin_amdgcn_mfma_f32_16x16x32_bf16(fB, bb[nt], acc[1][nt], 0, 0, 0);
            }
            a0 = na0; a1 = na1; b0 = nb0; b1 = nb1;
        }

#pragma unroll
        for (int i = 0; i < 2; ++i)
#pragma unroll
            for (int nt = 0; nt < 8; ++nt) {
                int col = nt * 16 + m;
#pragma unroll
                for (int r = 0; r < 4; ++r) {
                    int row = row0 + i * 16 + quad * 4 + r;
                    if (row < NN) outd[(size_t)row * FHID + col] = f2bf(acc[i][nt][r]);
                }
            }
    }
}

// ---------------- SpMM1 + bias + relu + GEMM2 (fused): support2 = relu(A@support1+b1)@W2 ----
// Wave-per-row grid-stride. Gather phase as R9 (32-edge unrolled, readlane
// descriptors). Wave ends with h-row in regs (lane j: cols 2j,2j+1).
// Matvec: readlane broadcasts chunk j; halves split k-parity (k=2j+s);
// W2 staged in 16KB LDS, read w2l[64j+lane] (conflict-free); one
// shfl_xor(32) combines; lanes 0-31 store bf16 col c. h never hits memory.
__global__ __launch_bounds__(256) void spmm1_fused(const int* __restrict__ rowptr,
                                                   const int2* __restrict__ epack,
                                                   const unsigned short* __restrict__ dense,
                                                   const float* __restrict__ b1,
                                                   const float* __restrict__ W2,
                                                   unsigned short* __restrict__ support2) {
    __shared__ float w2l[FHID * FOUT];  // 16KB, layout = W2 row-major
    const int t = threadIdx.x;
#pragma unroll
    for (int i = 0; i < 16; ++i) w2l[t + i * 256] = W2[t + i * 256];
    __syncthreads();

    const int lane = t & 63;
    const int sl16 = lane & 15;
    const int sfts = (lane >> 5) ? 0 : 16;  // chunk-extract shift for this half
    const unsigned* d32 = (const unsigned*)dense;
    const float2 bb = *(const float2*)(b1 + lane * 2);
    const int nwaves = gridDim.x * 4;

    for (int row = blockIdx.x * 4 + (t >> 6); row < NN; row += nwaves) {
        const int start = __builtin_amdgcn_readfirstlane(rowptr[row]);
        const int cnt = __builtin_amdgcn_readfirstlane(rowptr[row + 1]) - start;
        float acc0 = 0.f, acc1 = 0.f;

        int j = 0;
        for (; j + 32 <= cnt; j += 32) {
            int2 p0 = epack[start + j + sl16];
            int2 p1 = epack[start + j + 16 + sl16];
            unsigned d[32];
#pragma unroll
            for (int k = 0; k < 16; ++k) {
                int c = __builtin_amdgcn_readlane(p0.x, k);
                d[k] = d32[((size_t)c << 6) + lane];
            }
#pragma unroll
            for (int k = 0; k < 16; ++k) {
                int c = __builtin_amdgcn_readlane(p1.x, k);
                d[16 + k] = d32[((size_t)c << 6) + lane];
            }
#pragma unroll
            for (int k = 0; k < 16; ++k) {
                float v = __int_as_float(__builtin_amdgcn_readlane(p0.y, k));
                acc0 = fmaf(v, bflo(d[k]), acc0);
                acc1 = fmaf(v, bfhi(d[k]), acc1);
            }
#pragma unroll
            for (int k = 0; k < 16; ++k) {
                float v = __int_as_float(__builtin_amdgcn_readlane(p1.y, k));
                acc0 = fmaf(v, bflo(d[16 + k]), acc0);
                acc1 = fmaf(v, bfhi(d[16 + k]), acc1);
            }
        }
        if (j + 16 <= cnt) {
            int2 p = epack[start + j + sl16];
            unsigned d[16];
#pragma unroll
            for (int k = 0; k < 16; ++k) {
                int c = __builtin_amdgcn_readlane(p.x, k);
                d[k] = d32[((size_t)c << 6) + lane];
            }
#pragma unroll
            for (int k = 0; k < 16; ++k) {
                float v = __int_as_float(__builtin_amdgcn_readlane(p.y, k));
                acc0 = fmaf(v, bflo(d[k]), acc0);
                acc1 = fmaf(v, bfhi(d[k]), acc1);
            }
            j += 16;
        }
        const int rem = cnt - j;
        if (rem > 0) {
            int idx = j + (sl16 < rem ? sl16 : rem - 1);
            int2 p = epack[start + idx];
            unsigned d[16];
#pragma unroll
            for (int k = 0; k < 16; ++k) {
                int c = __builtin_amdgcn_readlane(p.x, k);
                c = (k < rem) ? c : 0;
                d[k] = d32[((size_t)c << 6) + lane];
            }
#pragma unroll
            for (int k = 0; k < 16; ++k) {
                float v = (k < rem) ? __int_as_float(__builtin_amdgcn_readlane(p.y, k)) : 0.f;
                acc0 = fmaf(v, bflo(d[k]), acc0);
                acc1 = fmaf(v, bfhi(d[k]), acc1);
            }
        }
        // bias + relu; pack lane's h chunk (cols 2*lane, 2*lane+1)
        float h0 = fmaxf(acc0 + bb.x, 0.f);
        float h1 = fmaxf(acc1 + bb.y, 0.f);
        unsigned packed = (unsigned)f2bf(h0) | ((unsigned)f2bf(h1) << 16);
        // fused gemm2: partial over k = 2j+s (s = lane>>5), col c = lane&31
        float p = 0.f;
#pragma unroll
        for (int jj = 0; jj < 64; ++jj) {
            unsigned pk = (unsigned)__builtin_amdgcn_readlane(packed, jj);
            float hv = __uint_as_float((pk << sfts) & 0xffff0000u);
            p = fmaf(hv, w2l[jj * 64 + lane], p);
        }
        p += __shfl_xor(p, 32, 64);
        if (lane < 32) support2[(size_t)row * FOUT + lane] = f2bf(p);
    }
}

// ------- SpMM2 + bias + log_softmax (fp32 out) -------
__global__ __launch_bounds__(256) void spmm2_kernel(const int* __restrict__ rowptr,
                                                    const int2* __restrict__ epack,
                                                    const unsigned short* __restrict__ dense,
                                                    const float* __restrict__ b2,
                                                    float* __restrict__ out) {
    const int lane = threadIdx.x & 63;
    const int row = blockIdx.x * 4 + (threadIdx.x >> 6);
    const int start = __builtin_amdgcn_readfirstlane(rowptr[row]);
    const int cnt = __builtin_amdgcn_readfirstlane(rowptr[row + 1]) - start;
    const int quad = lane >> 4;
    const int sl16 = lane & 15;
    const unsigned* d32 = (const unsigned*)dense;
    float acc0 = 0.f, acc1 = 0.f;

    int j = 0;
    for (; j + 16 <= cnt; j += 16) {
        int2 p = epack[start + j + sl16];
        unsigned d[4];
        float vv[4];
#pragma unroll
        for (int k = 0; k < 16; ++k) {
            int c = __builtin_amdgcn_readlane(p.x, k);
            int v = __builtin_amdgcn_readlane(p.y, k);
            if ((k >> 2) == quad) {
                d[k & 3] = d32[((size_t)c << 4) + sl16];
                vv[k & 3] = __int_as_float(v);
            }
        }
#pragma unroll
        for (int k = 0; k < 4; ++k) {
            acc0 = fmaf(vv[k], bflo(d[k]), acc0);
            acc1 = fmaf(vv[k], bfhi(d[k]), acc1);
        }
    }
    const int rem = cnt - j;
    if (rem > 0) {
        int idx = j + (sl16 < rem ? sl16 : rem - 1);
        int2 p = epack[start + idx];
        unsigned d[4];
        float vv[4];
#pragma unroll
        for (int k = 0; k < 4; ++k) { d[k] = 0; vv[k] = 0.f; }
#pragma unroll
        for (int k = 0; k < 16; ++k) {
            int c = __builtin_amdgcn_readlane(p.x, k);
            int v = __builtin_amdgcn_readlane(p.y, k);
            c = (k < rem) ? c : 0;
            if ((k >> 2) == quad) {
                d[k & 3] = d32[((size_t)c << 4) + sl16];
                vv[k & 3] = (k < rem) ? __int_as_float(v) : 0.f;
            }
        }
#pragma unroll
        for (int k = 0; k < 4; ++k) {
            acc0 = fmaf(vv[k], bflo(d[k]), acc0);
            acc1 = fmaf(vv[k], bfhi(d[k]), acc1);
        }
    }
    // combine quad partials: all lanes end with totals for cols 2*sl16(+1)
    acc0 += __shfl_xor(acc0, 16, 64);
    acc0 += __shfl_xor(acc0, 32, 64);
    acc1 += __shfl_xor(acc1, 16, 64);
    acc1 += __shfl_xor(acc1, 32, 64);
    float2 bb = *(const float2*)(b2 + sl16 * 2);
    acc0 += bb.x;
    acc1 += bb.y;
    float m = fmaxf(acc0, acc1);
#pragma unroll
    for (int mask = 8; mask >= 1; mask >>= 1) m = fmaxf(m, __shfl_xor(m, mask, 64));
    float ssum = expf(acc0 - m) + expf(acc1 - m);
#pragma unroll
    for (int mask = 8; mask >= 1; mask >>= 1) ssum += __shfl_xor(ssum, mask, 64);
    float lse = m + logf(ssum);
    if (lane < 16) {
        float2 st = make_float2(acc0 - lse, acc1 - lse);
        *(float2*)(out + (size_t)row * FOUT + sl16 * 2) = st;
    }
}

extern "C" void kernel_launch(void* const* d_in, const int* in_sizes, int n_in,
                              void* d_out, int out_size, void* d_ws, size_t ws_size,
                              hipStream_t stream) {
    const float* x = (const float*)d_in[0];
    const int* erow = (const int*)d_in[1];
    const int* ecol = (const int*)d_in[2];
    const float* eval = (const float*)d_in[3];
    const float* W1 = (const float*)d_in[4];
    const float* b1 = (const float*)d_in[5];
    const float* W2 = (const float*)d_in[6];
    const float* b2 = (const float*)d_in[7];
    float* out = (float*)d_out;

    char* ws = (char*)d_ws;
    size_t off_b = 0;
    auto walloc = [&](size_t bytes) -> void* {
        void* p = ws + off_b;
        off_b = (off_b + bytes + 255) & ~(size_t)255;
        return p;
    };
    int2* epack = (int2*)walloc((size_t)NE * 8);
    int* rowptr = (int*)walloc((size_t)(NN + 1) * 4);
    int* cntG = (int*)walloc((size_t)TOT * 4);
    int* off = (int*)walloc((size_t)TOT * 4);
    int* partials = (int*)walloc(4096);
    unsigned short* W1t = (unsigned short*)walloc((size_t)FHID * FIN * 2);
    int2* bcolval = (int2*)walloc((size_t)NE * 8);
    unsigned short* support1 = (unsigned short*)walloc((size_t)NN * FHID * 2);
    unsigned short* support2 = (unsigned short*)walloc((size_t)NN * FOUT * 2);

    fused_prep_hist<<<NPART + 256, 256, 0, stream>>>(W1, W1t, erow, cntG);
    scan1_kernel<<<NSCAN1, 256, 0, stream>>>(cntG, off, partials);
    scan2_kernel<<<1, 512, 0, stream>>>(partials);
    scatter_part<<<NPART, 512, 0, stream>>>(erow, ecol, eval, off, partials, bcolval);
    fused_csr_gemm1<<<NBUCK + GG1, 256, 0, stream>>>(off, partials, bcolval, rowptr,
                                                     epack, x, W1t, support1);
    spmm1_fused<<<2048, 256, 0, stream>>>(rowptr, epack, support1, b1, W2, support2);
    spmm2_kernel<<<NN / 4, 256, 0, stream>>>(rowptr, epack, support2, b2, out);
}